// Round 1
// baseline (644.674 us; speedup 1.0000x reference)
//
#include <hip/hip_runtime.h>
#include <math.h>
#include <stdint.h>

// ============================================================================
// RelationalBlock: 4x (rmsnorm -> attn(mask) -> +res) -> rmsnorm -> SwiGLU -> +res
// B=2 S=1024 D=1024 H=16 hd=64 DFF=4096. All GEMMs bf16-MFMA (fp32 accum).
// Masks are index-structured => computed in-kernel (bool inputs ignored):
//   L0 col: j%32==i%32 (32 keys), L1 feat: j/128==i/128 (128 keys),
//   L2 nbr: |i-j|<=64 (<=192-wide band), L3 full.
// ============================================================================

typedef __attribute__((ext_vector_type(8))) short bf16x8;
typedef __attribute__((ext_vector_type(4))) float f32x4;
typedef unsigned short ushort_t;
typedef unsigned int uint_t;

#define DEV static __device__ __forceinline__

DEV float bf2f(ushort_t u) { union { uint_t i; float f; } v; v.i = ((uint_t)u) << 16; return v.f; }
DEV ushort_t f2bf(float f) {             // round-to-nearest-even bf16
  union { float f; uint_t i; } v; v.f = f;
  uint_t r = v.i + 0x7fffu + ((v.i >> 16) & 1u);
  return (ushort_t)(r >> 16);
}
DEV uint_t pk2(ushort_t a, ushort_t b) { return (uint_t)a | ((uint_t)b << 16); }

DEV void gld16(const ushort_t* g, ushort_t* l) {   // async global->LDS, 16B/lane
  __builtin_amdgcn_global_load_lds((const __attribute__((address_space(1))) void*)g,
                                   (__attribute__((address_space(3))) void*)l, 16, 0, 0);
}

// ---------------------------------------------------------------------------
// Weight transpose+convert: src fp32 [R][C] -> dst bf16 [C-rows][R] (B^T form)
// ---------------------------------------------------------------------------
struct Src16 { const float* p[16]; };

__global__ __launch_bounds__(256) void transpose16(Src16 s, ushort_t* __restrict__ qkvT,
                                                   ushort_t* __restrict__ woT) {
  __shared__ float tile[32][33];
  const int mz = blockIdx.z;                 // 0..15: layer=mz>>2, which=mz&3 (q,k,v,o)
  const float* __restrict__ src = s.p[mz];
  const int l = mz >> 2, which = mz & 3;
  ushort_t* dst = (which < 3) ? (qkvT + (size_t)l*3072*1024 + (size_t)which*1024*1024)
                              : (woT  + (size_t)l*1024*1024);
  const int tx = threadIdx.x & 31, ty = threadIdx.x >> 5;
  const int r0 = blockIdx.y*32, c0 = blockIdx.x*32;
#pragma unroll
  for (int i = 0; i < 4; i++) tile[ty + 8*i][tx] = src[(size_t)(r0 + ty + 8*i)*1024 + c0 + tx];
  __syncthreads();
#pragma unroll
  for (int i = 0; i < 4; i++) dst[(size_t)(c0 + ty + 8*i)*1024 + r0 + tx] = f2bf(tile[tx][ty + 8*i]);
}

__global__ __launch_bounds__(256) void transpose_cvt(const float* __restrict__ src,
    ushort_t* __restrict__ dst, int R, int C, int row_off) {
  __shared__ float tile[32][33];
  const int tx = threadIdx.x & 31, ty = threadIdx.x >> 5;
  const int r0 = blockIdx.y*32, c0 = blockIdx.x*32;
#pragma unroll
  for (int i = 0; i < 4; i++) tile[ty + 8*i][tx] = src[(size_t)(r0 + ty + 8*i)*C + c0 + tx];
  __syncthreads();
#pragma unroll
  for (int i = 0; i < 4; i++)
    dst[(size_t)(row_off + c0 + ty + 8*i)*R + r0 + tx] = f2bf(tile[tx][ty + 8*i]);
}

// ---------------------------------------------------------------------------
// RMSNorm: fp32 in -> bf16 out (one block per row of 1024)
// ---------------------------------------------------------------------------
__global__ __launch_bounds__(256) void rmsnorm_k(const float* __restrict__ x,
    const float* __restrict__ w, ushort_t* __restrict__ out) {
  const int row = blockIdx.x, t = threadIdx.x;
  const float4 v = ((const float4*)(x + (size_t)row*1024))[t];
  float ss = v.x*v.x + v.y*v.y + v.z*v.z + v.w*v.w;
#pragma unroll
  for (int m = 32; m; m >>= 1) ss += __shfl_xor(ss, m);
  __shared__ float red[4];
  if ((t & 63) == 0) red[t >> 6] = ss;
  __syncthreads();
  const float tot = red[0] + red[1] + red[2] + red[3];
  const float rs = rsqrtf(tot * (1.0f/1024.0f) + 1.1920929e-07f);
  const float4 wv = ((const float4*)w)[t];
  uint2 o;
  o.x = pk2(f2bf(v.x*rs*wv.x), f2bf(v.y*rs*wv.y));
  o.y = pk2(f2bf(v.z*rs*wv.z), f2bf(v.w*rs*wv.w));
  *(uint2*)&out[(size_t)row*1024 + t*4] = o;
}

// ---------------------------------------------------------------------------
// GEMM: C[M][N] = A[M][K](bf16) * BT[N][K](bf16)^T, m97-style (128-tile, BK=64,
// global_load_lds w16, mfma 16x16x32 bf16). EPI 0: bf16 out. EPI 1: fp32 out = resid+acc.
// ---------------------------------------------------------------------------
template<int BM, int BN, int EPI>
__global__ __launch_bounds__(256, 2) void gemm_bt(
    const ushort_t* __restrict__ A, const ushort_t* __restrict__ BT,
    void* __restrict__ Cout, const float* __restrict__ resid, int M, int N, int K) {
  constexpr int BK = 64;
  __shared__ ushort_t Al[BM*BK];
  __shared__ ushort_t Bl[BN*BK];
  const int t = threadIdx.x, lane = t & 63;
  const int l15 = lane & 15, l4 = lane >> 4;
  const int m0 = blockIdx.y * BM, n0 = blockIdx.x * BN;
  constexpr int WM = BM/2, WN = BN/2, FM = WM/16, FN = WN/16;
  const int wm = ((t >> 6) >> 1) * WM;
  const int wn = ((t >> 6) & 1) * WN;
  const f32x4 zf = {0.f, 0.f, 0.f, 0.f};
  f32x4 acc[FM][FN];
#pragma unroll
  for (int m = 0; m < FM; m++)
#pragma unroll
    for (int n = 0; n < FN; n++) acc[m][n] = zf;
  constexpr int CA = (BM*BK)/(256*8), CB = (BN*BK)/(256*8);
  for (int k0 = 0; k0 < K; k0 += BK) {
#pragma unroll
    for (int i = 0; i < CA; i++) {
      const int c = i*256 + t;
      gld16(&A[(size_t)(m0 + (c >> 3))*K + k0 + (c & 7)*8], &Al[c*8]);
    }
#pragma unroll
    for (int i = 0; i < CB; i++) {
      const int c = i*256 + t;
      gld16(&BT[(size_t)(n0 + (c >> 3))*K + k0 + (c & 7)*8], &Bl[c*8]);
    }
    __syncthreads();
#pragma unroll
    for (int kc = 0; kc < BK; kc += 32) {
      bf16x8 af[FM], bfr[FN];
#pragma unroll
      for (int m = 0; m < FM; m++) af[m] = *(const bf16x8*)&Al[(wm + m*16 + l15)*BK + kc + l4*8];
#pragma unroll
      for (int n = 0; n < FN; n++) bfr[n] = *(const bf16x8*)&Bl[(wn + n*16 + l15)*BK + kc + l4*8];
#pragma unroll
      for (int m = 0; m < FM; m++)
#pragma unroll
        for (int n = 0; n < FN; n++)
          acc[m][n] = __builtin_amdgcn_mfma_f32_16x16x32_bf16(af[m], bfr[n], acc[m][n], 0, 0, 0);
    }
    __syncthreads();
  }
  // epilogue: C row = 4*(lane>>4)+r, col = lane&15 (m89-verified layout)
#pragma unroll
  for (int m = 0; m < FM; m++)
#pragma unroll
    for (int n = 0; n < FN; n++)
#pragma unroll
      for (int r = 0; r < 4; r++) {
        const int row = m0 + wm + m*16 + l4*4 + r;
        const int col = n0 + wn + n*16 + l15;
        const size_t idx = (size_t)row*N + col;
        const float v = acc[m][n][r];
        if (EPI == 0) ((ushort_t*)Cout)[idx] = f2bf(v);
        else          ((float*)Cout)[idx] = resid[idx] + v;
      }
}

// ---------------------------------------------------------------------------
// col attention: block = (c,h,b); 32 strided queries x 32 strided keys, fp32 vector
// ---------------------------------------------------------------------------
__global__ __launch_bounds__(256) void attn_col_k(const ushort_t* __restrict__ qkv,
                                                  ushort_t* __restrict__ O) {
  __shared__ float Qs[32][65], Ks[32][65], Vs[32][65], P[32][33];
  const int c = blockIdx.x, h = blockIdx.y, b = blockIdx.z, t = threadIdx.x;
  const size_t base = (size_t)b*1024*3072 + h*64;
  for (int e = t; e < 2048; e += 256) {
    const int u = e >> 6, d = e & 63;
    const size_t rb = base + (size_t)(c + 32*u)*3072 + d;
    Qs[u][d] = bf2f(qkv[rb]);
    Ks[u][d] = bf2f(qkv[rb + 1024]);
    Vs[u][d] = bf2f(qkv[rb + 2048]);
  }
  __syncthreads();
  const int u = t >> 3, kq = (t & 7)*4;
  float sc[4] = {0.f, 0.f, 0.f, 0.f};
  for (int d = 0; d < 64; d++) {
    const float q = Qs[u][d];
#pragma unroll
    for (int j = 0; j < 4; j++) sc[j] += q * Ks[kq + j][d];
  }
#pragma unroll
  for (int j = 0; j < 4; j++) P[u][kq + j] = sc[j] * 0.125f;
  __syncthreads();
  if (t < 32) {
    float mx = P[t][0];
    for (int j = 1; j < 32; j++) mx = fmaxf(mx, P[t][j]);
    float sum = 0.f;
    for (int j = 0; j < 32; j++) { const float p = __expf(P[t][j] - mx); P[t][j] = p; sum += p; }
    const float inv = 1.0f / sum;
    for (int j = 0; j < 32; j++) P[t][j] *= inv;
  }
  __syncthreads();
  const int dg = (t & 7)*8;
  float o[8] = {0.f,0.f,0.f,0.f,0.f,0.f,0.f,0.f};
  for (int k = 0; k < 32; k++) {
    const float p = P[u][k];
#pragma unroll
    for (int j = 0; j < 8; j++) o[j] += p * Vs[k][dg + j];
  }
  uint4 w4;
  w4.x = pk2(f2bf(o[0]), f2bf(o[1])); w4.y = pk2(f2bf(o[2]), f2bf(o[3]));
  w4.z = pk2(f2bf(o[4]), f2bf(o[5])); w4.w = pk2(f2bf(o[6]), f2bf(o[7]));
  *(uint4*)&O[base/3072*0 + (size_t)(b*1024 + c + 32*u)*1024 + h*64 + dg] = w4;
}

// ---------------------------------------------------------------------------
// MFMA flash attention. MASK: 0=feat(128 block), 1=nbr(band 64), 2=full.
// Block = 64 q-rows (16/wave), k-tiles of 32. K LDS padded; V staged transposed.
// ---------------------------------------------------------------------------
template<int MASK>
__global__ __launch_bounds__(256) void attn_flash_k(const ushort_t* __restrict__ qkv,
                                                    ushort_t* __restrict__ O) {
  constexpr int KP = 72, VP = 40, PP = 40;   // padded LDS row strides (elems)
  __shared__ ushort_t Kl[32*KP];
  __shared__ ushort_t Vtl[64*VP];
  __shared__ ushort_t Pl[4][16*PP];
  const int t = threadIdx.x, lane = t & 63, wave = t >> 6;
  const int l15 = lane & 15, l4 = lane >> 4;
  const int qt = blockIdx.x, h = blockIdx.y, b = blockIdx.z;
  const int q0 = qt*64;
  const size_t base = (size_t)b*1024*3072 + h*64;
  const int qrow = q0 + wave*16 + l15;
  const bf16x8 qf0 = *(const bf16x8*)&qkv[base + (size_t)qrow*3072 + l4*8];
  const bf16x8 qf1 = *(const bf16x8*)&qkv[base + (size_t)qrow*3072 + 32 + l4*8];
  int klo, khi;
  if (MASK == 0)      { klo = q0 & ~127; khi = klo + 128; }
  else if (MASK == 1) { klo = (q0 >= 64) ? q0 - 64 : 0; khi = (q0 + 128 < 1024) ? q0 + 128 : 1024; }
  else                { klo = 0; khi = 1024; }
  const f32x4 zf = {0.f, 0.f, 0.f, 0.f};
  f32x4 of[4];
#pragma unroll
  for (int n = 0; n < 4; n++) of[n] = zf;
  float mrow[4], lrow[4];
#pragma unroll
  for (int r = 0; r < 4; r++) { mrow[r] = -INFINITY; lrow[r] = 0.f; }
  const int skrow = t >> 3, sdb = (t & 7)*8;

  for (int kb = klo; kb < khi; kb += 32) {
    { // stage K (row-major, padded) and V (transposed)
      const size_t rb = base + (size_t)(kb + skrow)*3072 + sdb;
      const bf16x8 kv = *(const bf16x8*)&qkv[rb + 1024];
      const bf16x8 vv = *(const bf16x8*)&qkv[rb + 2048];
      *(bf16x8*)&Kl[skrow*KP + sdb] = kv;
#pragma unroll
      for (int j = 0; j < 8; j++) Vtl[(sdb + j)*VP + skrow] = (ushort_t)vv[j];
    }
    __syncthreads();
    // scores: S[16q x 32k] per wave = Q(16x64) @ K^T
    f32x4 sf0 = zf, sf1 = zf;
    {
      const bf16x8 k00 = *(const bf16x8*)&Kl[(l15)*KP + l4*8];
      const bf16x8 k01 = *(const bf16x8*)&Kl[(l15)*KP + 32 + l4*8];
      const bf16x8 k10 = *(const bf16x8*)&Kl[(16 + l15)*KP + l4*8];
      const bf16x8 k11 = *(const bf16x8*)&Kl[(16 + l15)*KP + 32 + l4*8];
      sf0 = __builtin_amdgcn_mfma_f32_16x16x32_bf16(qf0, k00, sf0, 0, 0, 0);
      sf0 = __builtin_amdgcn_mfma_f32_16x16x32_bf16(qf1, k01, sf0, 0, 0, 0);
      sf1 = __builtin_amdgcn_mfma_f32_16x16x32_bf16(qf0, k10, sf1, 0, 0, 0);
      sf1 = __builtin_amdgcn_mfma_f32_16x16x32_bf16(qf1, k11, sf1, 0, 0, 0);
    }
    float s0[4], s1[4], tmax[4];
#pragma unroll
    for (int r = 0; r < 4; r++) {
      float a = sf0[r]*0.125f, bb = sf1[r]*0.125f;
      if (MASK == 1) {
        const int qg = q0 + wave*16 + l4*4 + r;
        const int d0 = qg - (kb + l15), d1 = qg - (kb + 16 + l15);
        if (d0 > 64 || d0 < -64) a = -INFINITY;
        if (d1 > 64 || d1 < -64) bb = -INFINITY;
      }
      s0[r] = a; s1[r] = bb;
      tmax[r] = fmaxf(a, bb);
    }
#pragma unroll
    for (int mk = 1; mk < 16; mk <<= 1)
#pragma unroll
      for (int r = 0; r < 4; r++) tmax[r] = fmaxf(tmax[r], __shfl_xor(tmax[r], mk));
    float fac[4], psum[4];
#pragma unroll
    for (int r = 0; r < 4; r++) {
      const float mn = fmaxf(mrow[r], tmax[r]);
      float p0, p1;
      if (mn == -INFINITY) { fac[r] = 1.0f; p0 = 0.f; p1 = 0.f; }  // all-masked tile row
      else {
        fac[r] = __expf(mrow[r] - mn);     // expf(-inf)=0 on first tile
        p0 = __expf(s0[r] - mn); p1 = __expf(s1[r] - mn);
        mrow[r] = mn;
      }
      psum[r] = p0 + p1;
      Pl[wave][(l4*4 + r)*PP + l15]      = f2bf(p0);
      Pl[wave][(l4*4 + r)*PP + 16 + l15] = f2bf(p1);
    }
#pragma unroll
    for (int mk = 1; mk < 16; mk <<= 1)
#pragma unroll
      for (int r = 0; r < 4; r++) psum[r] += __shfl_xor(psum[r], mk);
#pragma unroll
    for (int r = 0; r < 4; r++) lrow[r] = lrow[r]*fac[r] + psum[r];
#pragma unroll
    for (int n = 0; n < 4; n++)
#pragma unroll
      for (int r = 0; r < 4; r++) of[n][r] *= fac[r];
    // PV: O[16q x 64d] += P(16x32) @ V(32x64); same-wave P RAW ordered by lgkmcnt
    const bf16x8 pa = *(const bf16x8*)&Pl[wave][l15*PP + l4*8];
#pragma unroll
    for (int n = 0; n < 4; n++) {
      const bf16x8 vf = *(const bf16x8*)&Vtl[(n*16 + l15)*VP + l4*8];
      of[n] = __builtin_amdgcn_mfma_f32_16x16x32_bf16(pa, vf, of[n], 0, 0, 0);
    }
    __syncthreads();
  }
#pragma unroll
  for (int n = 0; n < 4; n++)
#pragma unroll
    for (int r = 0; r < 4; r++) {
      const int qg = q0 + wave*16 + l4*4 + r;
      O[(size_t)(b*1024 + qg)*1024 + h*64 + n*16 + l15] = f2bf(of[n][r] / lrow[r]);
    }
}

// ---------------------------------------------------------------------------
// SwiGLU: hmid[m][j] = silu(gu[m][j]) * gu[m][4096+j]   (gate cols 0..4095)
// ---------------------------------------------------------------------------
__global__ __launch_bounds__(256) void swiglu_k(const ushort_t* __restrict__ gu,
                                                ushort_t* __restrict__ out) {
  const size_t idx = (size_t)blockIdx.x*256 + threadIdx.x;   // 8 elems per thread
  const size_t m = idx >> 9, j8 = (idx & 511) << 3;
  const bf16x8 g8 = *(const bf16x8*)&gu[m*8192 + j8];
  const bf16x8 u8 = *(const bf16x8*)&gu[m*8192 + 4096 + j8];
  ushort_t o[8];
#pragma unroll
  for (int i = 0; i < 8; i++) {
    const float g = bf2f((ushort_t)g8[i]);
    const float u = bf2f((ushort_t)u8[i]);
    o[i] = f2bf(u * g / (1.0f + __expf(-g)));
  }
  uint4 w4;
  w4.x = pk2(o[0], o[1]); w4.y = pk2(o[2], o[3]); w4.z = pk2(o[4], o[5]); w4.w = pk2(o[6], o[7]);
  *(uint4*)&out[m*4096 + j8] = w4;
}

// ---------------------------------------------------------------------------
extern "C" void kernel_launch(void* const* d_in, const int* in_sizes, int n_in,
                              void* d_out, int out_size, void* d_ws, size_t ws_size,
                              hipStream_t stream) {
  (void)in_sizes; (void)n_in; (void)out_size; (void)ws_size;
  const float* x_in = (const float*)d_in[0];
  const float* norm[5] = { (const float*)d_in[5], (const float*)d_in[10], (const float*)d_in[15],
                           (const float*)d_in[20], (const float*)d_in[25] };
  // workspace layout (~140 MB)
  char* w = (char*)d_ws;
  auto alloc = [&](size_t bytes) { char* p = w; w += (bytes + 255) & ~(size_t)255; return p; };
  ushort_t* qkvT = (ushort_t*)alloc(4ull*3072*1024*2);
  ushort_t* woT  = (ushort_t*)alloc(4ull*1024*1024*2);
  ushort_t* guT  = (ushort_t*)alloc(8192ull*1024*2);
  ushort_t* dnT  = (ushort_t*)alloc(4096ull*1024*2);
  float*    xbuf = (float*)  alloc(2048ull*1024*4);
  ushort_t* xn   = (ushort_t*)alloc(2048ull*1024*2);
  ushort_t* qkv  = (ushort_t*)alloc(2048ull*3072*2);
  ushort_t* attO = (ushort_t*)alloc(2048ull*1024*2);
  ushort_t* gu   = (ushort_t*)alloc(2048ull*8192*2);
  ushort_t* hmid = (ushort_t*)alloc(2048ull*4096*2);

  // weight prep: transpose + bf16 convert
  Src16 s;
  for (int l = 0; l < 4; l++) {
    s.p[l*4 + 0] = (const float*)d_in[6 + l*5];
    s.p[l*4 + 1] = (const float*)d_in[7 + l*5];
    s.p[l*4 + 2] = (const float*)d_in[8 + l*5];
    s.p[l*4 + 3] = (const float*)d_in[9 + l*5];
  }
  transpose16<<<dim3(32, 32, 16), 256, 0, stream>>>(s, qkvT, woT);
  transpose_cvt<<<dim3(128, 32), 256, 0, stream>>>((const float*)d_in[27], guT, 1024, 4096, 0);    // w_gate
  transpose_cvt<<<dim3(128, 32), 256, 0, stream>>>((const float*)d_in[26], guT, 1024, 4096, 4096); // w_up
  transpose_cvt<<<dim3(32, 128), 256, 0, stream>>>((const float*)d_in[28], dnT, 4096, 1024, 0);    // w_down

  const float* xcur = x_in;
  for (int l = 0; l < 4; l++) {
    rmsnorm_k<<<2048, 256, 0, stream>>>(xcur, norm[l], xn);
    gemm_bt<128,128,0><<<dim3(3072/128, 2048/128), 256, 0, stream>>>(
        xn, qkvT + (size_t)l*3072*1024, qkv, nullptr, 2048, 3072, 1024);
    if (l == 0)      attn_col_k        <<<dim3(32, 16, 2), 256, 0, stream>>>(qkv, attO);
    else if (l == 1) attn_flash_k<0>   <<<dim3(16, 16, 2), 256, 0, stream>>>(qkv, attO);
    else if (l == 2) attn_flash_k<1>   <<<dim3(16, 16, 2), 256, 0, stream>>>(qkv, attO);
    else             attn_flash_k<2>   <<<dim3(16, 16, 2), 256, 0, stream>>>(qkv, attO);
    gemm_bt<128,64,1><<<dim3(1024/64, 2048/128), 256, 0, stream>>>(
        attO, woT + (size_t)l*1024*1024, xbuf, xcur, 2048, 1024, 1024);
    xcur = xbuf;
  }
  rmsnorm_k<<<2048, 256, 0, stream>>>(xcur, norm[4], xn);
  gemm_bt<128,128,0><<<dim3(8192/128, 2048/128), 256, 0, stream>>>(xn, guT, gu, nullptr, 2048, 8192, 1024);
  swiglu_k<<<4096, 256, 0, stream>>>(gu, hmid);
  gemm_bt<128,64,1><<<dim3(1024/64, 2048/128), 256, 0, stream>>>(hmid, dnT, d_out, xbuf, 2048, 1024, 4096);
}

// Round 2
// 617.520 us; speedup vs baseline: 1.0440x; 1.0440x over previous
//
#include <hip/hip_runtime.h>
#include <math.h>
#include <stdint.h>

// ============================================================================
// RelationalBlock: 4x (rmsnorm -> attn(mask) -> +res) -> rmsnorm -> SwiGLU -> +res
// B=2 S=1024 D=1024 H=16 hd=64 DFF=4096. All GEMMs bf16-MFMA (fp32 accum).
// Masks are index-structured => computed in-kernel:
//   L0 col: j%32==i%32 (32 keys), L1 feat: j/128==i/128 (128), L2 nbr: |i-j|<=64, L3 full.
// R1 fix: N=1024 GEMMs were grid-starved (256 blocks, occ 10%, 70us each).
//   -> smaller tiles + split-K atomics: WO 64x64xSK2 (1024 blk), down 64x64xSK4
//   (2048 blk), QKV 64x128 (768 blk). Residual via fp32 atomicAdd into
//   pre-copied buffer. XCD-bijective swizzle on all GEMM grids.
// ============================================================================

typedef __attribute__((ext_vector_type(8))) short bf16x8;
typedef __attribute__((ext_vector_type(4))) float f32x4;
typedef unsigned short ushort_t;
typedef unsigned int uint_t;

#define DEV static __device__ __forceinline__

DEV float bf2f(ushort_t u) { union { uint_t i; float f; } v; v.i = ((uint_t)u) << 16; return v.f; }
DEV ushort_t f2bf(float f) {             // round-to-nearest-even bf16
  union { float f; uint_t i; } v; v.f = f;
  uint_t r = v.i + 0x7fffu + ((v.i >> 16) & 1u);
  return (ushort_t)(r >> 16);
}
DEV uint_t pk2(ushort_t a, ushort_t b) { return (uint_t)a | ((uint_t)b << 16); }

DEV void gld16(const ushort_t* g, ushort_t* l) {   // async global->LDS, 16B/lane
  __builtin_amdgcn_global_load_lds((const __attribute__((address_space(1))) void*)g,
                                   (__attribute__((address_space(3))) void*)l, 16, 0, 0);
}

// ---------------------------------------------------------------------------
// Weight transpose+convert: src fp32 [R][C] -> dst bf16 [C-rows][R] (B^T form)
// ---------------------------------------------------------------------------
struct Src16 { const float* p[16]; };

__global__ __launch_bounds__(256) void transpose16(Src16 s, ushort_t* __restrict__ qkvT,
                                                   ushort_t* __restrict__ woT) {
  __shared__ float tile[32][33];
  const int mz = blockIdx.z;                 // 0..15: layer=mz>>2, which=mz&3 (q,k,v,o)
  const float* __restrict__ src = s.p[mz];
  const int l = mz >> 2, which = mz & 3;
  ushort_t* dst = (which < 3) ? (qkvT + (size_t)l*3072*1024 + (size_t)which*1024*1024)
                              : (woT  + (size_t)l*1024*1024);
  const int tx = threadIdx.x & 31, ty = threadIdx.x >> 5;
  const int r0 = blockIdx.y*32, c0 = blockIdx.x*32;
#pragma unroll
  for (int i = 0; i < 4; i++) tile[ty + 8*i][tx] = src[(size_t)(r0 + ty + 8*i)*1024 + c0 + tx];
  __syncthreads();
#pragma unroll
  for (int i = 0; i < 4; i++) dst[(size_t)(c0 + ty + 8*i)*1024 + r0 + tx] = f2bf(tile[tx][ty + 8*i]);
}

__global__ __launch_bounds__(256) void transpose_cvt(const float* __restrict__ src,
    ushort_t* __restrict__ dst, int R, int C, int row_off) {
  __shared__ float tile[32][33];
  const int tx = threadIdx.x & 31, ty = threadIdx.x >> 5;
  const int r0 = blockIdx.y*32, c0 = blockIdx.x*32;
#pragma unroll
  for (int i = 0; i < 4; i++) tile[ty + 8*i][tx] = src[(size_t)(r0 + ty + 8*i)*C + c0 + tx];
  __syncthreads();
#pragma unroll
  for (int i = 0; i < 4; i++)
    dst[(size_t)(row_off + c0 + ty + 8*i)*R + r0 + tx] = f2bf(tile[tx][ty + 8*i]);
}

// ---------------------------------------------------------------------------
// fp32 copy (residual init): 4 elems/thread
// ---------------------------------------------------------------------------
__global__ __launch_bounds__(256) void copy_f32(const float* __restrict__ src,
                                                float* __restrict__ dst) {
  const size_t i = (size_t)blockIdx.x*256 + threadIdx.x;
  ((float4*)dst)[i] = ((const float4*)src)[i];
}

// ---------------------------------------------------------------------------
// RMSNorm: fp32 in -> bf16 out (one block per row of 1024)
// ---------------------------------------------------------------------------
__global__ __launch_bounds__(256) void rmsnorm_k(const float* __restrict__ x,
    const float* __restrict__ w, ushort_t* __restrict__ out) {
  const int row = blockIdx.x, t = threadIdx.x;
  const float4 v = ((const float4*)(x + (size_t)row*1024))[t];
  float ss = v.x*v.x + v.y*v.y + v.z*v.z + v.w*v.w;
#pragma unroll
  for (int m = 32; m; m >>= 1) ss += __shfl_xor(ss, m);
  __shared__ float red[4];
  if ((t & 63) == 0) red[t >> 6] = ss;
  __syncthreads();
  const float tot = red[0] + red[1] + red[2] + red[3];
  const float rs = rsqrtf(tot * (1.0f/1024.0f) + 1.1920929e-07f);
  const float4 wv = ((const float4*)w)[t];
  uint2 o;
  o.x = pk2(f2bf(v.x*rs*wv.x), f2bf(v.y*rs*wv.y));
  o.y = pk2(f2bf(v.z*rs*wv.z), f2bf(v.w*rs*wv.w));
  *(uint2*)&out[(size_t)row*1024 + t*4] = o;
}

// ---------------------------------------------------------------------------
// GEMM: C[M][N] (+)= A[M][K](bf16) * BT[N][K](bf16)^T. m97 structure, BK=64,
// global_load_lds w16, mfma 16x16x32 bf16, 4 waves in 2x2.
// EPI 0: bf16 store (SPLITK must be 1). EPI 2: fp32 atomicAdd (split-K /
// residual accumulate; dest pre-initialized with residual).
// Grid: (N/BN, M/BM, SPLITK). XCD-bijective swizzle when (gx*gy)%8==0.
// ---------------------------------------------------------------------------
template<int BM, int BN, int EPI, int SPLITK>
__global__ __launch_bounds__(256, 2) void gemm_bt(
    const ushort_t* __restrict__ A, const ushort_t* __restrict__ BT,
    void* __restrict__ Cout, int M, int N, int K) {
  constexpr int BK = 64;
  __shared__ ushort_t Al[BM*BK];
  __shared__ ushort_t Bl[BN*BK];
  const int t = threadIdx.x, lane = t & 63;
  const int l15 = lane & 15, l4 = lane >> 4;
  // XCD-aware bijective block swizzle (nwg % 8 == 0 for all our grids)
  int bid = blockIdx.y * gridDim.x + blockIdx.x;
  const int nwg = gridDim.x * gridDim.y;
  if ((nwg & 7) == 0) bid = (bid & 7) * (nwg >> 3) + (bid >> 3);
  const int n0 = (bid % gridDim.x) * BN;
  const int m0 = (bid / gridDim.x) * BM;
  constexpr int WM = BM/2, WN = BN/2, FM = WM/16, FN = WN/16;
  const int wm = ((t >> 6) >> 1) * WM;
  const int wn = ((t >> 6) & 1) * WN;
  const f32x4 zf = {0.f, 0.f, 0.f, 0.f};
  f32x4 acc[FM][FN];
#pragma unroll
  for (int m = 0; m < FM; m++)
#pragma unroll
    for (int n = 0; n < FN; n++) acc[m][n] = zf;
  constexpr int CA = (BM*BK)/(256*8), CB = (BN*BK)/(256*8);
  const int kz = blockIdx.z * (K / SPLITK);
  for (int k0 = kz; k0 < kz + K / SPLITK; k0 += BK) {
#pragma unroll
    for (int i = 0; i < CA; i++) {
      const int c = i*256 + t;
      gld16(&A[(size_t)(m0 + (c >> 3))*K + k0 + (c & 7)*8], &Al[c*8]);
    }
#pragma unroll
    for (int i = 0; i < CB; i++) {
      const int c = i*256 + t;
      gld16(&BT[(size_t)(n0 + (c >> 3))*K + k0 + (c & 7)*8], &Bl[c*8]);
    }
    __syncthreads();
#pragma unroll
    for (int kc = 0; kc < BK; kc += 32) {
      bf16x8 af[FM], bfr[FN];
#pragma unroll
      for (int m = 0; m < FM; m++) af[m] = *(const bf16x8*)&Al[(wm + m*16 + l15)*BK + kc + l4*8];
#pragma unroll
      for (int n = 0; n < FN; n++) bfr[n] = *(const bf16x8*)&Bl[(wn + n*16 + l15)*BK + kc + l4*8];
#pragma unroll
      for (int m = 0; m < FM; m++)
#pragma unroll
        for (int n = 0; n < FN; n++)
          acc[m][n] = __builtin_amdgcn_mfma_f32_16x16x32_bf16(af[m], bfr[n], acc[m][n], 0, 0, 0);
    }
    __syncthreads();
  }
  // epilogue: C row = 4*(lane>>4)+r, col = lane&15 (m89-verified layout)
#pragma unroll
  for (int m = 0; m < FM; m++)
#pragma unroll
    for (int n = 0; n < FN; n++)
#pragma unroll
      for (int r = 0; r < 4; r++) {
        const int row = m0 + wm + m*16 + l4*4 + r;
        const int col = n0 + wn + n*16 + l15;
        const size_t idx = (size_t)row*N + col;
        const float v = acc[m][n][r];
        if (EPI == 0) ((ushort_t*)Cout)[idx] = f2bf(v);
        else          atomicAdd(&((float*)Cout)[idx], v);
      }
}

// ---------------------------------------------------------------------------
// col attention: block = (c,h,b); 32 strided queries x 32 strided keys, fp32 vector
// ---------------------------------------------------------------------------
__global__ __launch_bounds__(256) void attn_col_k(const ushort_t* __restrict__ qkv,
                                                  ushort_t* __restrict__ O) {
  __shared__ float Qs[32][65], Ks[32][65], Vs[32][65], P[32][33];
  const int c = blockIdx.x, h = blockIdx.y, b = blockIdx.z, t = threadIdx.x;
  const size_t base = (size_t)b*1024*3072 + h*64;
  for (int e = t; e < 2048; e += 256) {
    const int u = e >> 6, d = e & 63;
    const size_t rb = base + (size_t)(c + 32*u)*3072 + d;
    Qs[u][d] = bf2f(qkv[rb]);
    Ks[u][d] = bf2f(qkv[rb + 1024]);
    Vs[u][d] = bf2f(qkv[rb + 2048]);
  }
  __syncthreads();
  const int u = t >> 3, kq = (t & 7)*4;
  float sc[4] = {0.f, 0.f, 0.f, 0.f};
  for (int d = 0; d < 64; d++) {
    const float q = Qs[u][d];
#pragma unroll
    for (int j = 0; j < 4; j++) sc[j] += q * Ks[kq + j][d];
  }
#pragma unroll
  for (int j = 0; j < 4; j++) P[u][kq + j] = sc[j] * 0.125f;
  __syncthreads();
  if (t < 32) {
    float mx = P[t][0];
    for (int j = 1; j < 32; j++) mx = fmaxf(mx, P[t][j]);
    float sum = 0.f;
    for (int j = 0; j < 32; j++) { const float p = __expf(P[t][j] - mx); P[t][j] = p; sum += p; }
    const float inv = 1.0f / sum;
    for (int j = 0; j < 32; j++) P[t][j] *= inv;
  }
  __syncthreads();
  const int dg = (t & 7)*8;
  float o[8] = {0.f,0.f,0.f,0.f,0.f,0.f,0.f,0.f};
  for (int k = 0; k < 32; k++) {
    const float p = P[u][k];
#pragma unroll
    for (int j = 0; j < 8; j++) o[j] += p * Vs[k][dg + j];
  }
  uint4 w4;
  w4.x = pk2(f2bf(o[0]), f2bf(o[1])); w4.y = pk2(f2bf(o[2]), f2bf(o[3]));
  w4.z = pk2(f2bf(o[4]), f2bf(o[5])); w4.w = pk2(f2bf(o[6]), f2bf(o[7]));
  *(uint4*)&O[(size_t)(b*1024 + c + 32*u)*1024 + h*64 + dg] = w4;
}

// ---------------------------------------------------------------------------
// MFMA flash attention. MASK: 0=feat(128 block), 1=nbr(band 64), 2=full.
// Block = 64 q-rows (16/wave), k-tiles of 32. K LDS padded; V staged transposed.
// ---------------------------------------------------------------------------
template<int MASK>
__global__ __launch_bounds__(256) void attn_flash_k(const ushort_t* __restrict__ qkv,
                                                    ushort_t* __restrict__ O) {
  constexpr int KP = 72, VP = 40, PP = 40;   // padded LDS row strides (elems)
  __shared__ ushort_t Kl[32*KP];
  __shared__ ushort_t Vtl[64*VP];
  __shared__ ushort_t Pl[4][16*PP];
  const int t = threadIdx.x, lane = t & 63, wave = t >> 6;
  const int l15 = lane & 15, l4 = lane >> 4;
  const int qt = blockIdx.x, h = blockIdx.y, b = blockIdx.z;
  const int q0 = qt*64;
  const size_t base = (size_t)b*1024*3072 + h*64;
  const int qrow = q0 + wave*16 + l15;
  const bf16x8 qf0 = *(const bf16x8*)&qkv[base + (size_t)qrow*3072 + l4*8];
  const bf16x8 qf1 = *(const bf16x8*)&qkv[base + (size_t)qrow*3072 + 32 + l4*8];
  int klo, khi;
  if (MASK == 0)      { klo = q0 & ~127; khi = klo + 128; }
  else if (MASK == 1) { klo = (q0 >= 64) ? q0 - 64 : 0; khi = (q0 + 128 < 1024) ? q0 + 128 : 1024; }
  else                { klo = 0; khi = 1024; }
  const f32x4 zf = {0.f, 0.f, 0.f, 0.f};
  f32x4 of[4];
#pragma unroll
  for (int n = 0; n < 4; n++) of[n] = zf;
  float mrow[4], lrow[4];
#pragma unroll
  for (int r = 0; r < 4; r++) { mrow[r] = -INFINITY; lrow[r] = 0.f; }
  const int skrow = t >> 3, sdb = (t & 7)*8;

  for (int kb = klo; kb < khi; kb += 32) {
    { // stage K (row-major, padded) and V (transposed)
      const size_t rb = base + (size_t)(kb + skrow)*3072 + sdb;
      const bf16x8 kv = *(const bf16x8*)&qkv[rb + 1024];
      const bf16x8 vv = *(const bf16x8*)&qkv[rb + 2048];
      *(bf16x8*)&Kl[skrow*KP + sdb] = kv;
#pragma unroll
      for (int j = 0; j < 8; j++) Vtl[(sdb + j)*VP + skrow] = (ushort_t)vv[j];
    }
    __syncthreads();
    // scores: S[16q x 32k] per wave = Q(16x64) @ K^T
    f32x4 sf0 = zf, sf1 = zf;
    {
      const bf16x8 k00 = *(const bf16x8*)&Kl[(l15)*KP + l4*8];
      const bf16x8 k01 = *(const bf16x8*)&Kl[(l15)*KP + 32 + l4*8];
      const bf16x8 k10 = *(const bf16x8*)&Kl[(16 + l15)*KP + l4*8];
      const bf16x8 k11 = *(const bf16x8*)&Kl[(16 + l15)*KP + 32 + l4*8];
      sf0 = __builtin_amdgcn_mfma_f32_16x16x32_bf16(qf0, k00, sf0, 0, 0, 0);
      sf0 = __builtin_amdgcn_mfma_f32_16x16x32_bf16(qf1, k01, sf0, 0, 0, 0);
      sf1 = __builtin_amdgcn_mfma_f32_16x16x32_bf16(qf0, k10, sf1, 0, 0, 0);
      sf1 = __builtin_amdgcn_mfma_f32_16x16x32_bf16(qf1, k11, sf1, 0, 0, 0);
    }
    float s0[4], s1[4], tmax[4];
#pragma unroll
    for (int r = 0; r < 4; r++) {
      float a = sf0[r]*0.125f, bb = sf1[r]*0.125f;
      if (MASK == 1) {
        const int qg = q0 + wave*16 + l4*4 + r;
        const int d0 = qg - (kb + l15), d1 = qg - (kb + 16 + l15);
        if (d0 > 64 || d0 < -64) a = -INFINITY;
        if (d1 > 64 || d1 < -64) bb = -INFINITY;
      }
      s0[r] = a; s1[r] = bb;
      tmax[r] = fmaxf(a, bb);
    }
#pragma unroll
    for (int mk = 1; mk < 16; mk <<= 1)
#pragma unroll
      for (int r = 0; r < 4; r++) tmax[r] = fmaxf(tmax[r], __shfl_xor(tmax[r], mk));
    float fac[4], psum[4];
#pragma unroll
    for (int r = 0; r < 4; r++) {
      const float mn = fmaxf(mrow[r], tmax[r]);
      float p0, p1;
      if (mn == -INFINITY) { fac[r] = 1.0f; p0 = 0.f; p1 = 0.f; }  // all-masked tile row
      else {
        fac[r] = __expf(mrow[r] - mn);     // expf(-inf)=0 on first tile
        p0 = __expf(s0[r] - mn); p1 = __expf(s1[r] - mn);
        mrow[r] = mn;
      }
      psum[r] = p0 + p1;
      Pl[wave][(l4*4 + r)*PP + l15]      = f2bf(p0);
      Pl[wave][(l4*4 + r)*PP + 16 + l15] = f2bf(p1);
    }
#pragma unroll
    for (int mk = 1; mk < 16; mk <<= 1)
#pragma unroll
      for (int r = 0; r < 4; r++) psum[r] += __shfl_xor(psum[r], mk);
#pragma unroll
    for (int r = 0; r < 4; r++) lrow[r] = lrow[r]*fac[r] + psum[r];
#pragma unroll
    for (int n = 0; n < 4; n++)
#pragma unroll
      for (int r = 0; r < 4; r++) of[n][r] *= fac[r];
    // PV: O[16q x 64d] += P(16x32) @ V(32x64); same-wave P RAW ordered by lgkmcnt
    const bf16x8 pa = *(const bf16x8*)&Pl[wave][l15*PP + l4*8];
#pragma unroll
    for (int n = 0; n < 4; n++) {
      const bf16x8 vf = *(const bf16x8*)&Vtl[(n*16 + l15)*VP + l4*8];
      of[n] = __builtin_amdgcn_mfma_f32_16x16x32_bf16(pa, vf, of[n], 0, 0, 0);
    }
    __syncthreads();
  }
#pragma unroll
  for (int n = 0; n < 4; n++)
#pragma unroll
    for (int r = 0; r < 4; r++) {
      const int qg = q0 + wave*16 + l4*4 + r;
      O[(size_t)(b*1024 + qg)*1024 + h*64 + n*16 + l15] = f2bf(of[n][r] / lrow[r]);
    }
}

// ---------------------------------------------------------------------------
// SwiGLU: hmid[m][j] = silu(gu[m][j]) * gu[m][4096+j]   (gate cols 0..4095)
// ---------------------------------------------------------------------------
__global__ __launch_bounds__(256) void swiglu_k(const ushort_t* __restrict__ gu,
                                                ushort_t* __restrict__ out) {
  const size_t idx = (size_t)blockIdx.x*256 + threadIdx.x;   // 8 elems per thread
  const size_t m = idx >> 9, j8 = (idx & 511) << 3;
  const bf16x8 g8 = *(const bf16x8*)&gu[m*8192 + j8];
  const bf16x8 u8 = *(const bf16x8*)&gu[m*8192 + 4096 + j8];
  ushort_t o[8];
#pragma unroll
  for (int i = 0; i < 8; i++) {
    const float g = bf2f((ushort_t)g8[i]);
    const float u = bf2f((ushort_t)u8[i]);
    o[i] = f2bf(u * g / (1.0f + __expf(-g)));
  }
  uint4 w4;
  w4.x = pk2(o[0], o[1]); w4.y = pk2(o[2], o[3]); w4.z = pk2(o[4], o[5]); w4.w = pk2(o[6], o[7]);
  *(uint4*)&out[m*4096 + j8] = w4;
}

// ---------------------------------------------------------------------------
extern "C" void kernel_launch(void* const* d_in, const int* in_sizes, int n_in,
                              void* d_out, int out_size, void* d_ws, size_t ws_size,
                              hipStream_t stream) {
  (void)in_sizes; (void)n_in; (void)out_size; (void)ws_size;
  const float* x_in = (const float*)d_in[0];
  const float* norm[5] = { (const float*)d_in[5], (const float*)d_in[10], (const float*)d_in[15],
                           (const float*)d_in[20], (const float*)d_in[25] };
  // workspace layout (~140 MB)
  char* w = (char*)d_ws;
  auto alloc = [&](size_t bytes) { char* p = w; w += (bytes + 255) & ~(size_t)255; return p; };
  ushort_t* qkvT = (ushort_t*)alloc(4ull*3072*1024*2);
  ushort_t* woT  = (ushort_t*)alloc(4ull*1024*1024*2);
  ushort_t* guT  = (ushort_t*)alloc(8192ull*1024*2);
  ushort_t* dnT  = (ushort_t*)alloc(4096ull*1024*2);
  float*    xbuf = (float*)  alloc(2048ull*1024*4);
  ushort_t* xn   = (ushort_t*)alloc(2048ull*1024*2);
  ushort_t* qkv  = (ushort_t*)alloc(2048ull*3072*2);
  ushort_t* attO = (ushort_t*)alloc(2048ull*1024*2);
  ushort_t* gu   = (ushort_t*)alloc(2048ull*8192*2);
  ushort_t* hmid = (ushort_t*)alloc(2048ull*4096*2);

  // weight prep: transpose + bf16 convert
  Src16 s;
  for (int l = 0; l < 4; l++) {
    s.p[l*4 + 0] = (const float*)d_in[6 + l*5];
    s.p[l*4 + 1] = (const float*)d_in[7 + l*5];
    s.p[l*4 + 2] = (const float*)d_in[8 + l*5];
    s.p[l*4 + 3] = (const float*)d_in[9 + l*5];
  }
  transpose16<<<dim3(32, 32, 16), 256, 0, stream>>>(s, qkvT, woT);
  transpose_cvt<<<dim3(128, 32), 256, 0, stream>>>((const float*)d_in[27], guT, 1024, 4096, 0);    // w_gate
  transpose_cvt<<<dim3(128, 32), 256, 0, stream>>>((const float*)d_in[26], guT, 1024, 4096, 4096); // w_up
  transpose_cvt<<<dim3(32, 128), 256, 0, stream>>>((const float*)d_in[28], dnT, 4096, 1024, 0);    // w_down

  // residual stream lives in xbuf (fp32); WO/down GEMMs atomically accumulate
  copy_f32<<<2048, 256, 0, stream>>>(x_in, xbuf);

  for (int l = 0; l < 4; l++) {
    rmsnorm_k<<<2048, 256, 0, stream>>>(xbuf, norm[l], xn);
    gemm_bt<64,128,0,1><<<dim3(3072/128, 2048/64), 256, 0, stream>>>(
        xn, qkvT + (size_t)l*3072*1024, qkv, 2048, 3072, 1024);
    if (l == 0)      attn_col_k        <<<dim3(32, 16, 2), 256, 0, stream>>>(qkv, attO);
    else if (l == 1) attn_flash_k<0>   <<<dim3(16, 16, 2), 256, 0, stream>>>(qkv, attO);
    else if (l == 2) attn_flash_k<1>   <<<dim3(16, 16, 2), 256, 0, stream>>>(qkv, attO);
    else             attn_flash_k<2>   <<<dim3(16, 16, 2), 256, 0, stream>>>(qkv, attO);
    // WO: split-K=2, atomic accumulate into xbuf (residual already there)
    gemm_bt<64,64,2,2><<<dim3(1024/64, 2048/64, 2), 256, 0, stream>>>(
        attO, woT + (size_t)l*1024*1024, xbuf, 2048, 1024, 1024);
  }
  rmsnorm_k<<<2048, 256, 0, stream>>>(xbuf, norm[4], xn);
  gemm_bt<128,128,0,1><<<dim3(8192/128, 2048/128), 256, 0, stream>>>(xn, guT, gu, 2048, 8192, 1024);
  swiglu_k<<<4096, 256, 0, stream>>>(gu, hmid);
  // down-proj: d_out = xbuf + hmid @ w_down, split-K=4 atomic
  copy_f32<<<2048, 256, 0, stream>>>(xbuf, (float*)d_out);
  gemm_bt<64,64,2,4><<<dim3(1024/64, 2048/64, 4), 256, 0, stream>>>(
      hmid, dnT, d_out, 2048, 1024, 4096);
}

// Round 3
// 600.219 us; speedup vs baseline: 1.0741x; 1.0288x over previous
//
#include <hip/hip_runtime.h>
#include <math.h>
#include <stdint.h>

// ============================================================================
// RelationalBlock: 4x (rmsnorm -> attn(mask) -> +res) -> rmsnorm -> SwiGLU -> +res
// B=2 S=1024 D=1024 H=16 hd=64 DFF=4096. All GEMMs bf16-MFMA (fp32 accum).
// Masks are index-structured => computed in-kernel:
//   L0 col: j%32==i%32 (32 keys), L1 feat: j/128==i/128 (128), L2 nbr: |i-j|<=64, L3 full.
// R2 fix: attention was the top cost (68us full layer): 8-way LDS bank
//   conflicts (9.7M/dispatch), 32-key tiles (barrier/reduce overhead), no
//   prefetch, grid-capped occupancy. -> stride-66 LDS (<=2-way everywhere),
//   64-key tiles, register prefetch (T14), setprio (T5), K-split=2 for the
//   full-mask layer with (O,m,l) partials + merge kernel.
// ============================================================================

typedef __attribute__((ext_vector_type(8))) short bf16x8;
typedef __attribute__((ext_vector_type(4))) float f32x4;
typedef unsigned short ushort_t;
typedef unsigned int uint_t;

#define DEV static __device__ __forceinline__

DEV float bf2f(ushort_t u) { union { uint_t i; float f; } v; v.i = ((uint_t)u) << 16; return v.f; }
DEV ushort_t f2bf(float f) {             // round-to-nearest-even bf16
  union { float f; uint_t i; } v; v.f = f;
  uint_t r = v.i + 0x7fffu + ((v.i >> 16) & 1u);
  return (ushort_t)(r >> 16);
}
DEV uint_t pk2(ushort_t a, ushort_t b) { return (uint_t)a | ((uint_t)b << 16); }

DEV void gld16(const ushort_t* g, ushort_t* l) {   // async global->LDS, 16B/lane
  __builtin_amdgcn_global_load_lds((const __attribute__((address_space(1))) void*)g,
                                   (__attribute__((address_space(3))) void*)l, 16, 0, 0);
}

// ---------------------------------------------------------------------------
// Weight transpose+convert: src fp32 [R][C] -> dst bf16 [C-rows][R] (B^T form)
// ---------------------------------------------------------------------------
struct Src16 { const float* p[16]; };

__global__ __launch_bounds__(256) void transpose16(Src16 s, ushort_t* __restrict__ qkvT,
                                                   ushort_t* __restrict__ woT) {
  __shared__ float tile[32][33];
  const int mz = blockIdx.z;                 // 0..15: layer=mz>>2, which=mz&3 (q,k,v,o)
  const float* __restrict__ src = s.p[mz];
  const int l = mz >> 2, which = mz & 3;
  ushort_t* dst = (which < 3) ? (qkvT + (size_t)l*3072*1024 + (size_t)which*1024*1024)
                              : (woT  + (size_t)l*1024*1024);
  const int tx = threadIdx.x & 31, ty = threadIdx.x >> 5;
  const int r0 = blockIdx.y*32, c0 = blockIdx.x*32;
#pragma unroll
  for (int i = 0; i < 4; i++) tile[ty + 8*i][tx] = src[(size_t)(r0 + ty + 8*i)*1024 + c0 + tx];
  __syncthreads();
#pragma unroll
  for (int i = 0; i < 4; i++) dst[(size_t)(c0 + ty + 8*i)*1024 + r0 + tx] = f2bf(tile[tx][ty + 8*i]);
}

__global__ __launch_bounds__(256) void transpose_cvt(const float* __restrict__ src,
    ushort_t* __restrict__ dst, int R, int C, int row_off) {
  __shared__ float tile[32][33];
  const int tx = threadIdx.x & 31, ty = threadIdx.x >> 5;
  const int r0 = blockIdx.y*32, c0 = blockIdx.x*32;
#pragma unroll
  for (int i = 0; i < 4; i++) tile[ty + 8*i][tx] = src[(size_t)(r0 + ty + 8*i)*C + c0 + tx];
  __syncthreads();
#pragma unroll
  for (int i = 0; i < 4; i++)
    dst[(size_t)(row_off + c0 + ty + 8*i)*R + r0 + tx] = f2bf(tile[tx][ty + 8*i]);
}

// ---------------------------------------------------------------------------
// fp32 copy (residual init): 4 elems/thread
// ---------------------------------------------------------------------------
__global__ __launch_bounds__(256) void copy_f32(const float* __restrict__ src,
                                                float* __restrict__ dst) {
  const size_t i = (size_t)blockIdx.x*256 + threadIdx.x;
  ((float4*)dst)[i] = ((const float4*)src)[i];
}

// ---------------------------------------------------------------------------
// RMSNorm: fp32 in -> bf16 out (one block per row of 1024)
// ---------------------------------------------------------------------------
__global__ __launch_bounds__(256) void rmsnorm_k(const float* __restrict__ x,
    const float* __restrict__ w, ushort_t* __restrict__ out) {
  const int row = blockIdx.x, t = threadIdx.x;
  const float4 v = ((const float4*)(x + (size_t)row*1024))[t];
  float ss = v.x*v.x + v.y*v.y + v.z*v.z + v.w*v.w;
#pragma unroll
  for (int m = 32; m; m >>= 1) ss += __shfl_xor(ss, m);
  __shared__ float red[4];
  if ((t & 63) == 0) red[t >> 6] = ss;
  __syncthreads();
  const float tot = red[0] + red[1] + red[2] + red[3];
  const float rs = rsqrtf(tot * (1.0f/1024.0f) + 1.1920929e-07f);
  const float4 wv = ((const float4*)w)[t];
  uint2 o;
  o.x = pk2(f2bf(v.x*rs*wv.x), f2bf(v.y*rs*wv.y));
  o.y = pk2(f2bf(v.z*rs*wv.z), f2bf(v.w*rs*wv.w));
  *(uint2*)&out[(size_t)row*1024 + t*4] = o;
}

// ---------------------------------------------------------------------------
// GEMM: C[M][N] (+)= A[M][K](bf16) * BT[N][K](bf16)^T. m97 structure, BK=64,
// global_load_lds w16, mfma 16x16x32 bf16, 4 waves in 2x2.
// EPI 0: bf16 store (SPLITK must be 1). EPI 2: fp32 atomicAdd.
// ---------------------------------------------------------------------------
template<int BM, int BN, int EPI, int SPLITK>
__global__ __launch_bounds__(256, 2) void gemm_bt(
    const ushort_t* __restrict__ A, const ushort_t* __restrict__ BT,
    void* __restrict__ Cout, int M, int N, int K) {
  constexpr int BK = 64;
  __shared__ ushort_t Al[BM*BK];
  __shared__ ushort_t Bl[BN*BK];
  const int t = threadIdx.x, lane = t & 63;
  const int l15 = lane & 15, l4 = lane >> 4;
  int bid = blockIdx.y * gridDim.x + blockIdx.x;
  const int nwg = gridDim.x * gridDim.y;
  if ((nwg & 7) == 0) bid = (bid & 7) * (nwg >> 3) + (bid >> 3);
  const int n0 = (bid % gridDim.x) * BN;
  const int m0 = (bid / gridDim.x) * BM;
  constexpr int WM = BM/2, WN = BN/2, FM = WM/16, FN = WN/16;
  const int wm = ((t >> 6) >> 1) * WM;
  const int wn = ((t >> 6) & 1) * WN;
  const f32x4 zf = {0.f, 0.f, 0.f, 0.f};
  f32x4 acc[FM][FN];
#pragma unroll
  for (int m = 0; m < FM; m++)
#pragma unroll
    for (int n = 0; n < FN; n++) acc[m][n] = zf;
  constexpr int CA = (BM*BK)/(256*8), CB = (BN*BK)/(256*8);
  const int kz = blockIdx.z * (K / SPLITK);
  for (int k0 = kz; k0 < kz + K / SPLITK; k0 += BK) {
#pragma unroll
    for (int i = 0; i < CA; i++) {
      const int c = i*256 + t;
      gld16(&A[(size_t)(m0 + (c >> 3))*K + k0 + (c & 7)*8], &Al[c*8]);
    }
#pragma unroll
    for (int i = 0; i < CB; i++) {
      const int c = i*256 + t;
      gld16(&BT[(size_t)(n0 + (c >> 3))*K + k0 + (c & 7)*8], &Bl[c*8]);
    }
    __syncthreads();
#pragma unroll
    for (int kc = 0; kc < BK; kc += 32) {
      bf16x8 af[FM], bfr[FN];
#pragma unroll
      for (int m = 0; m < FM; m++) af[m] = *(const bf16x8*)&Al[(wm + m*16 + l15)*BK + kc + l4*8];
#pragma unroll
      for (int n = 0; n < FN; n++) bfr[n] = *(const bf16x8*)&Bl[(wn + n*16 + l15)*BK + kc + l4*8];
#pragma unroll
      for (int m = 0; m < FM; m++)
#pragma unroll
        for (int n = 0; n < FN; n++)
          acc[m][n] = __builtin_amdgcn_mfma_f32_16x16x32_bf16(af[m], bfr[n], acc[m][n], 0, 0, 0);
    }
    __syncthreads();
  }
#pragma unroll
  for (int m = 0; m < FM; m++)
#pragma unroll
    for (int n = 0; n < FN; n++)
#pragma unroll
      for (int r = 0; r < 4; r++) {
        const int row = m0 + wm + m*16 + l4*4 + r;
        const int col = n0 + wn + n*16 + l15;
        const size_t idx = (size_t)row*N + col;
        const float v = acc[m][n][r];
        if (EPI == 0) ((ushort_t*)Cout)[idx] = f2bf(v);
        else          atomicAdd(&((float*)Cout)[idx], v);
      }
}

// ---------------------------------------------------------------------------
// col attention: block = (c,h,b); 32 strided queries x 32 strided keys, fp32 vector
// ---------------------------------------------------------------------------
__global__ __launch_bounds__(256) void attn_col_k(const ushort_t* __restrict__ qkv,
                                                  ushort_t* __restrict__ O) {
  __shared__ float Qs[32][65], Ks[32][65], Vs[32][65], P[32][33];
  const int c = blockIdx.x, h = blockIdx.y, b = blockIdx.z, t = threadIdx.x;
  const size_t base = (size_t)b*1024*3072 + h*64;
  for (int e = t; e < 2048; e += 256) {
    const int u = e >> 6, d = e & 63;
    const size_t rb = base + (size_t)(c + 32*u)*3072 + d;
    Qs[u][d] = bf2f(qkv[rb]);
    Ks[u][d] = bf2f(qkv[rb + 1024]);
    Vs[u][d] = bf2f(qkv[rb + 2048]);
  }
  __syncthreads();
  const int u = t >> 3, kq = (t & 7)*4;
  float sc[4] = {0.f, 0.f, 0.f, 0.f};
  for (int d = 0; d < 64; d++) {
    const float q = Qs[u][d];
#pragma unroll
    for (int j = 0; j < 4; j++) sc[j] += q * Ks[kq + j][d];
  }
#pragma unroll
  for (int j = 0; j < 4; j++) P[u][kq + j] = sc[j] * 0.125f;
  __syncthreads();
  if (t < 32) {
    float mx = P[t][0];
    for (int j = 1; j < 32; j++) mx = fmaxf(mx, P[t][j]);
    float sum = 0.f;
    for (int j = 0; j < 32; j++) { const float p = __expf(P[t][j] - mx); P[t][j] = p; sum += p; }
    const float inv = 1.0f / sum;
    for (int j = 0; j < 32; j++) P[t][j] *= inv;
  }
  __syncthreads();
  const int dg = (t & 7)*8;
  float o[8] = {0.f,0.f,0.f,0.f,0.f,0.f,0.f,0.f};
  for (int k = 0; k < 32; k++) {
    const float p = P[u][k];
#pragma unroll
    for (int j = 0; j < 8; j++) o[j] += p * Vs[k][dg + j];
  }
  uint4 w4;
  w4.x = pk2(f2bf(o[0]), f2bf(o[1])); w4.y = pk2(f2bf(o[2]), f2bf(o[3]));
  w4.z = pk2(f2bf(o[4]), f2bf(o[5])); w4.w = pk2(f2bf(o[6]), f2bf(o[7]));
  *(uint4*)&O[(size_t)(b*1024 + c + 32*u)*1024 + h*64 + dg] = w4;
}

// ---------------------------------------------------------------------------
// MFMA flash attention, 64-key tiles, stride-66 LDS (<=2-way banks), register
// prefetch. MASK: 0=feat(128 block), 1=nbr(band 64), 2=full (NSPLIT k-split).
// Block = 64 q-rows (16/wave). NSPLIT>1: write unnormalized (O,m,l) partials.
// ---------------------------------------------------------------------------
template<int MASK, int NSPLIT>
__global__ __launch_bounds__(256) void attn_flash_k(const ushort_t* __restrict__ qkv,
    ushort_t* __restrict__ O, float* __restrict__ Opart, float* __restrict__ MLpart) {
  constexpr int LP = 66;   // row stride: LP/2==33 ==1 mod 32 -> <=2-way banks
  __shared__ ushort_t Kl[64*LP];
  __shared__ ushort_t Vt[64*LP];
  __shared__ ushort_t Pl[4][16*LP];
  const int t = threadIdx.x, lane = t & 63, wave = t >> 6;
  const int l15 = lane & 15, l4 = lane >> 4;
  const int qt = blockIdx.x, h = blockIdx.y;
  const int b = blockIdx.z / NSPLIT, sp = blockIdx.z % NSPLIT;
  const int q0 = qt*64;
  const size_t base = (size_t)b*1024*3072 + h*64;
  const int qrow = q0 + wave*16 + l15;
  const bf16x8 qf0 = *(const bf16x8*)&qkv[base + (size_t)qrow*3072 + l4*8];
  const bf16x8 qf1 = *(const bf16x8*)&qkv[base + (size_t)qrow*3072 + 32 + l4*8];
  int klo, khi;
  if (MASK == 0)      { klo = q0 & ~127; khi = klo + 128; }
  else if (MASK == 1) { klo = (q0 >= 64) ? q0 - 64 : 0; khi = (q0 + 128 < 1024) ? q0 + 128 : 1024; }
  else                { klo = sp * (1024/NSPLIT); khi = klo + 1024/NSPLIT; }
  // staging coords: K by (row=t>>2, 16 d), V by (row=lane, 16 d per wave)
  const int kr = t >> 2, kd = (t & 3)*16;
  const int vk = lane,  vd = wave*16;
  const ushort_t* kptr = qkv + base + 1024 + (size_t)kr*3072 + kd;
  const ushort_t* vptr = qkv + base + 2048 + (size_t)vk*3072 + vd;
  bf16x8 kg0 = *(const bf16x8*)&kptr[(size_t)klo*3072];
  bf16x8 kg1 = *(const bf16x8*)&kptr[(size_t)klo*3072 + 8];
  bf16x8 vg0 = *(const bf16x8*)&vptr[(size_t)klo*3072];
  bf16x8 vg1 = *(const bf16x8*)&vptr[(size_t)klo*3072 + 8];
  const f32x4 zf = {0.f, 0.f, 0.f, 0.f};
  f32x4 of[4];
#pragma unroll
  for (int n = 0; n < 4; n++) of[n] = zf;
  float mrow[4], lrow[4];
#pragma unroll
  for (int r = 0; r < 4; r++) { mrow[r] = -INFINITY; lrow[r] = 0.f; }

  for (int kb = klo; kb < khi; kb += 64) {
    // write staged tile (K row-major, V transposed)
    *(bf16x8*)&Kl[kr*LP + kd] = kg0;
    *(bf16x8*)&Kl[kr*LP + kd + 8] = kg1;
#pragma unroll
    for (int j = 0; j < 8; j++) Vt[(vd + j)*LP + vk] = (ushort_t)vg0[j];
#pragma unroll
    for (int j = 0; j < 8; j++) Vt[(vd + 8 + j)*LP + vk] = (ushort_t)vg1[j];
    __syncthreads();
    if (kb + 64 < khi) {   // T14: prefetch next tile into regs, hides under compute
      kg0 = *(const bf16x8*)&kptr[(size_t)(kb+64)*3072];
      kg1 = *(const bf16x8*)&kptr[(size_t)(kb+64)*3072 + 8];
      vg0 = *(const bf16x8*)&vptr[(size_t)(kb+64)*3072];
      vg1 = *(const bf16x8*)&vptr[(size_t)(kb+64)*3072 + 8];
    }
    // scores: S[16q x 64k] per wave = 8 MFMA
    f32x4 sf[4];
    __builtin_amdgcn_s_setprio(1);
#pragma unroll
    for (int s = 0; s < 4; s++) {
      const bf16x8 k0 = *(const bf16x8*)&Kl[(s*16 + l15)*LP + l4*8];
      const bf16x8 k1 = *(const bf16x8*)&Kl[(s*16 + l15)*LP + 32 + l4*8];
      sf[s] = __builtin_amdgcn_mfma_f32_16x16x32_bf16(qf0, k0, zf, 0, 0, 0);
      sf[s] = __builtin_amdgcn_mfma_f32_16x16x32_bf16(qf1, k1, sf[s], 0, 0, 0);
    }
    __builtin_amdgcn_s_setprio(0);
    // online softmax over 64 keys
    float sv[4][4], tmax[4];
#pragma unroll
    for (int r = 0; r < 4; r++) tmax[r] = -INFINITY;
#pragma unroll
    for (int s = 0; s < 4; s++)
#pragma unroll
      for (int r = 0; r < 4; r++) {
        float a = sf[s][r]*0.125f;
        if (MASK == 1) {
          const int d = (q0 + wave*16 + l4*4 + r) - (kb + s*16 + l15);
          if (d > 64 || d < -64) a = -INFINITY;
        }
        sv[s][r] = a;
        tmax[r] = fmaxf(tmax[r], a);
      }
#pragma unroll
    for (int mk = 1; mk < 16; mk <<= 1)
#pragma unroll
      for (int r = 0; r < 4; r++) tmax[r] = fmaxf(tmax[r], __shfl_xor(tmax[r], mk));
    float fac[4], psum[4];
#pragma unroll
    for (int r = 0; r < 4; r++) {
      const float mn = fmaxf(mrow[r], tmax[r]);
      psum[r] = 0.f;
      if (mn == -INFINITY) {     // fully-masked row-tile (defensive)
        fac[r] = 1.0f;
#pragma unroll
        for (int s = 0; s < 4; s++) {
          Pl[wave][(l4*4 + r)*LP + s*16 + l15] = 0;
        }
      } else {
        fac[r] = __expf(mrow[r] - mn);
        mrow[r] = mn;
#pragma unroll
        for (int s = 0; s < 4; s++) {
          const float p = __expf(sv[s][r] - mn);
          psum[r] += p;
          Pl[wave][(l4*4 + r)*LP + s*16 + l15] = f2bf(p);
        }
      }
    }
#pragma unroll
    for (int mk = 1; mk < 16; mk <<= 1)
#pragma unroll
      for (int r = 0; r < 4; r++) psum[r] += __shfl_xor(psum[r], mk);
#pragma unroll
    for (int r = 0; r < 4; r++) lrow[r] = lrow[r]*fac[r] + psum[r];
#pragma unroll
    for (int n = 0; n < 4; n++)
#pragma unroll
      for (int r = 0; r < 4; r++) of[n][r] *= fac[r];
    // PV: O[16q x 64d] += P(16x64) @ V(64x64) = 8 MFMA (same-wave RAW via lgkmcnt)
    const bf16x8 pa0 = *(const bf16x8*)&Pl[wave][l15*LP + l4*8];
    const bf16x8 pa1 = *(const bf16x8*)&Pl[wave][l15*LP + 32 + l4*8];
    __builtin_amdgcn_s_setprio(1);
#pragma unroll
    for (int n = 0; n < 4; n++) {
      const bf16x8 v0 = *(const bf16x8*)&Vt[(n*16 + l15)*LP + l4*8];
      const bf16x8 v1 = *(const bf16x8*)&Vt[(n*16 + l15)*LP + 32 + l4*8];
      of[n] = __builtin_amdgcn_mfma_f32_16x16x32_bf16(pa0, v0, of[n], 0, 0, 0);
      of[n] = __builtin_amdgcn_mfma_f32_16x16x32_bf16(pa1, v1, of[n], 0, 0, 0);
    }
    __builtin_amdgcn_s_setprio(0);
    __syncthreads();
  }
  if (NSPLIT == 1) {
#pragma unroll
    for (int n = 0; n < 4; n++)
#pragma unroll
      for (int r = 0; r < 4; r++) {
        const int qg = q0 + wave*16 + l4*4 + r;
        O[(size_t)(b*1024 + qg)*1024 + h*64 + n*16 + l15] = f2bf(of[n][r] / lrow[r]);
      }
  } else {
    // unnormalized partials: Opart[(sp*2+b)][q][h][d], ML float2 per row
#pragma unroll
    for (int r = 0; r < 4; r++) {
      const int qg = q0 + wave*16 + l4*4 + r;
      const size_t row = ((size_t)(sp*2 + b)*1024 + qg)*16 + h;
#pragma unroll
      for (int n = 0; n < 4; n++) Opart[row*64 + n*16 + l15] = of[n][r];
      if (l15 == 0) *(float2*)&MLpart[row*2] = make_float2(mrow[r], lrow[r]);
    }
  }
}

// merge 2 k-splits: O = (O0*e^{m0-m} + O1*e^{m1-m}) / (l0*e^{m0-m} + l1*e^{m1-m})
__global__ __launch_bounds__(256) void attn_merge_k(const float* __restrict__ Opart,
    const float* __restrict__ ML, ushort_t* __restrict__ O) {
  const int idx = blockIdx.x*256 + threadIdx.x;   // 2*1024*16*8 threads
  const int d8 = (idx & 7)*8;
  const int h  = (idx >> 3) & 15;
  const int q  = (idx >> 7) & 1023;
  const int b  = idx >> 17;
  const size_t r0 = ((size_t)b*1024 + q)*16 + h;
  const size_t r1 = ((size_t)(2 + b)*1024 + q)*16 + h;
  const float2 ml0 = *(const float2*)&ML[r0*2];
  const float2 ml1 = *(const float2*)&ML[r1*2];
  const float m = fmaxf(ml0.x, ml1.x);
  const float w0 = __expf(ml0.x - m), w1 = __expf(ml1.x - m);
  const float inv = 1.0f / (ml0.y*w0 + ml1.y*w1);
  const float4* o0 = (const float4*)&Opart[r0*64 + d8];
  const float4* o1 = (const float4*)&Opart[r1*64 + d8];
  ushort_t ob[8];
#pragma unroll
  for (int i = 0; i < 2; i++) {
    const float4 a = o0[i], c = o1[i];
    ob[i*4+0] = f2bf((a.x*w0 + c.x*w1)*inv);
    ob[i*4+1] = f2bf((a.y*w0 + c.y*w1)*inv);
    ob[i*4+2] = f2bf((a.z*w0 + c.z*w1)*inv);
    ob[i*4+3] = f2bf((a.w*w0 + c.w*w1)*inv);
  }
  uint4 w4;
  w4.x = pk2(ob[0], ob[1]); w4.y = pk2(ob[2], ob[3]);
  w4.z = pk2(ob[4], ob[5]); w4.w = pk2(ob[6], ob[7]);
  *(uint4*)&O[((size_t)b*1024 + q)*1024 + h*64 + d8] = w4;
}

// ---------------------------------------------------------------------------
// SwiGLU: hmid[m][j] = silu(gu[m][j]) * gu[m][4096+j]
// ---------------------------------------------------------------------------
__global__ __launch_bounds__(256) void swiglu_k(const ushort_t* __restrict__ gu,
                                                ushort_t* __restrict__ out) {
  const size_t idx = (size_t)blockIdx.x*256 + threadIdx.x;
  const size_t m = idx >> 9, j8 = (idx & 511) << 3;
  const bf16x8 g8 = *(const bf16x8*)&gu[m*8192 + j8];
  const bf16x8 u8 = *(const bf16x8*)&gu[m*8192 + 4096 + j8];
  ushort_t o[8];
#pragma unroll
  for (int i = 0; i < 8; i++) {
    const float g = bf2f((ushort_t)g8[i]);
    const float u = bf2f((ushort_t)u8[i]);
    o[i] = f2bf(u * g / (1.0f + __expf(-g)));
  }
  uint4 w4;
  w4.x = pk2(o[0], o[1]); w4.y = pk2(o[2], o[3]); w4.z = pk2(o[4], o[5]); w4.w = pk2(o[6], o[7]);
  *(uint4*)&out[m*4096 + j8] = w4;
}

// ---------------------------------------------------------------------------
extern "C" void kernel_launch(void* const* d_in, const int* in_sizes, int n_in,
                              void* d_out, int out_size, void* d_ws, size_t ws_size,
                              hipStream_t stream) {
  (void)in_sizes; (void)n_in; (void)out_size; (void)ws_size;
  const float* x_in = (const float*)d_in[0];
  const float* norm[5] = { (const float*)d_in[5], (const float*)d_in[10], (const float*)d_in[15],
                           (const float*)d_in[20], (const float*)d_in[25] };
  char* w = (char*)d_ws;
  auto alloc = [&](size_t bytes) { char* p = w; w += (bytes + 255) & ~(size_t)255; return p; };
  ushort_t* qkvT = (ushort_t*)alloc(4ull*3072*1024*2);
  ushort_t* woT  = (ushort_t*)alloc(4ull*1024*1024*2);
  ushort_t* guT  = (ushort_t*)alloc(8192ull*1024*2);
  ushort_t* dnT  = (ushort_t*)alloc(4096ull*1024*2);
  float*    xbuf = (float*)  alloc(2048ull*1024*4);
  ushort_t* xn   = (ushort_t*)alloc(2048ull*1024*2);
  ushort_t* qkv  = (ushort_t*)alloc(2048ull*3072*2);
  ushort_t* attO = (ushort_t*)alloc(2048ull*1024*2);
  ushort_t* gu   = (ushort_t*)alloc(2048ull*8192*2);
  ushort_t* hmid = (ushort_t*)alloc(2048ull*4096*2);
  // attention split partials alias FFN-only buffers (disjoint lifetimes):
  float* Opart  = (float*)gu;      // 4096*16*64*4 = 16.8MB <= 32MB
  float* MLpart = (float*)hmid;    // 4096*16*2*4  = 512KB  <= 16MB

  Src16 s;
  for (int l = 0; l < 4; l++) {
    s.p[l*4 + 0] = (const float*)d_in[6 + l*5];
    s.p[l*4 + 1] = (const float*)d_in[7 + l*5];
    s.p[l*4 + 2] = (const float*)d_in[8 + l*5];
    s.p[l*4 + 3] = (const float*)d_in[9 + l*5];
  }
  transpose16<<<dim3(32, 32, 16), 256, 0, stream>>>(s, qkvT, woT);
  transpose_cvt<<<dim3(128, 32), 256, 0, stream>>>((const float*)d_in[27], guT, 1024, 4096, 0);    // w_gate
  transpose_cvt<<<dim3(128, 32), 256, 0, stream>>>((const float*)d_in[26], guT, 1024, 4096, 4096); // w_up
  transpose_cvt<<<dim3(32, 128), 256, 0, stream>>>((const float*)d_in[28], dnT, 4096, 1024, 0);    // w_down

  copy_f32<<<2048, 256, 0, stream>>>(x_in, xbuf);

  for (int l = 0; l < 4; l++) {
    rmsnorm_k<<<2048, 256, 0, stream>>>(xbuf, norm[l], xn);
    gemm_bt<64,128,0,1><<<dim3(3072/128, 2048/64), 256, 0, stream>>>(
        xn, qkvT + (size_t)l*3072*1024, qkv, 2048, 3072, 1024);
    if (l == 0)      attn_col_k         <<<dim3(32, 16, 2), 256, 0, stream>>>(qkv, attO);
    else if (l == 1) attn_flash_k<0,1>  <<<dim3(16, 16, 2), 256, 0, stream>>>(qkv, attO, nullptr, nullptr);
    else if (l == 2) attn_flash_k<1,1>  <<<dim3(16, 16, 2), 256, 0, stream>>>(qkv, attO, nullptr, nullptr);
    else {
      attn_flash_k<2,2><<<dim3(16, 16, 4), 256, 0, stream>>>(qkv, nullptr, Opart, MLpart);
      attn_merge_k<<<1024, 256, 0, stream>>>(Opart, MLpart, attO);
    }
    gemm_bt<64,64,2,2><<<dim3(1024/64, 2048/64, 2), 256, 0, stream>>>(
        attO, woT + (size_t)l*1024*1024, xbuf, 2048, 1024, 1024);
  }
  rmsnorm_k<<<2048, 256, 0, stream>>>(xbuf, norm[4], xn);
  gemm_bt<128,128,0,1><<<dim3(8192/128, 2048/128), 256, 0, stream>>>(xn, guT, gu, 2048, 8192, 1024);
  swiglu_k<<<4096, 256, 0, stream>>>(gu, hmid);
  copy_f32<<<2048, 256, 0, stream>>>(xbuf, (float*)d_out);
  gemm_bt<64,64,2,4><<<dim3(1024/64, 2048/64, 4), 256, 0, stream>>>(
      hmid, dnT, d_out, 2048, 1024, 4096);
}

// Round 4
// 579.748 us; speedup vs baseline: 1.1120x; 1.0353x over previous
//
#include <hip/hip_runtime.h>
#include <math.h>
#include <stdint.h>

// ============================================================================
// RelationalBlock: 4x (rmsnorm -> attn(mask) -> +res) -> rmsnorm -> SwiGLU -> +res
// B=2 S=1024 D=1024 H=16 hd=64 DFF=4096. All GEMMs bf16-MFMA (fp32 accum).
// Masks are index-structured => computed in-kernel:
//   L0 col: j%32==i%32 (32 keys), L1 feat: j/128==i/128 (128), L2 nbr: |i-j|<=64, L3 full.
// R3 fixes (gemm-focused):
//  - 16-way LDS bank conflict in fragment ds_read (row stride 128B) fixed via
//    XOR chunk swizzle: pre-swizzled GLOBAL source (gld16 dest must stay
//    linear, m104/m173), read side chunk ^= l15&7. 12.58M conflicts -> ~0.
//  - bigger tiles: QKV 128x128 (384 blk), WO 128x64 SK2 (512 blk),
//    down 128x128 SK4 (512 blk, K=1024/split). 64^2 tiles had MFMA:ds 1.0.
// ============================================================================

typedef __attribute__((ext_vector_type(8))) short bf16x8;
typedef __attribute__((ext_vector_type(4))) float f32x4;
typedef unsigned short ushort_t;
typedef unsigned int uint_t;

#define DEV static __device__ __forceinline__

DEV float bf2f(ushort_t u) { union { uint_t i; float f; } v; v.i = ((uint_t)u) << 16; return v.f; }
DEV ushort_t f2bf(float f) {             // round-to-nearest-even bf16
  union { float f; uint_t i; } v; v.f = f;
  uint_t r = v.i + 0x7fffu + ((v.i >> 16) & 1u);
  return (ushort_t)(r >> 16);
}
DEV uint_t pk2(ushort_t a, ushort_t b) { return (uint_t)a | ((uint_t)b << 16); }

DEV void gld16(const ushort_t* g, ushort_t* l) {   // async global->LDS, 16B/lane
  __builtin_amdgcn_global_load_lds((const __attribute__((address_space(1))) void*)g,
                                   (__attribute__((address_space(3))) void*)l, 16, 0, 0);
}

// ---------------------------------------------------------------------------
// Weight transpose+convert: src fp32 [R][C] -> dst bf16 [C-rows][R] (B^T form)
// ---------------------------------------------------------------------------
struct Src16 { const float* p[16]; };

__global__ __launch_bounds__(256) void transpose16(Src16 s, ushort_t* __restrict__ qkvT,
                                                   ushort_t* __restrict__ woT) {
  __shared__ float tile[32][33];
  const int mz = blockIdx.z;                 // 0..15: layer=mz>>2, which=mz&3 (q,k,v,o)
  const float* __restrict__ src = s.p[mz];
  const int l = mz >> 2, which = mz & 3;
  ushort_t* dst = (which < 3) ? (qkvT + (size_t)l*3072*1024 + (size_t)which*1024*1024)
                              : (woT  + (size_t)l*1024*1024);
  const int tx = threadIdx.x & 31, ty = threadIdx.x >> 5;
  const int r0 = blockIdx.y*32, c0 = blockIdx.x*32;
#pragma unroll
  for (int i = 0; i < 4; i++) tile[ty + 8*i][tx] = src[(size_t)(r0 + ty + 8*i)*1024 + c0 + tx];
  __syncthreads();
#pragma unroll
  for (int i = 0; i < 4; i++) dst[(size_t)(c0 + ty + 8*i)*1024 + r0 + tx] = f2bf(tile[tx][ty + 8*i]);
}

__global__ __launch_bounds__(256) void transpose_cvt(const float* __restrict__ src,
    ushort_t* __restrict__ dst, int R, int C, int row_off) {
  __shared__ float tile[32][33];
  const int tx = threadIdx.x & 31, ty = threadIdx.x >> 5;
  const int r0 = blockIdx.y*32, c0 = blockIdx.x*32;
#pragma unroll
  for (int i = 0; i < 4; i++) tile[ty + 8*i][tx] = src[(size_t)(r0 + ty + 8*i)*C + c0 + tx];
  __syncthreads();
#pragma unroll
  for (int i = 0; i < 4; i++)
    dst[(size_t)(row_off + c0 + ty + 8*i)*R + r0 + tx] = f2bf(tile[tx][ty + 8*i]);
}

// ---------------------------------------------------------------------------
// fp32 copy (residual init): 4 elems/thread
// ---------------------------------------------------------------------------
__global__ __launch_bounds__(256) void copy_f32(const float* __restrict__ src,
                                                float* __restrict__ dst) {
  const size_t i = (size_t)blockIdx.x*256 + threadIdx.x;
  ((float4*)dst)[i] = ((const float4*)src)[i];
}

// ---------------------------------------------------------------------------
// RMSNorm: fp32 in -> bf16 out (one block per row of 1024)
// ---------------------------------------------------------------------------
__global__ __launch_bounds__(256) void rmsnorm_k(const float* __restrict__ x,
    const float* __restrict__ w, ushort_t* __restrict__ out) {
  const int row = blockIdx.x, t = threadIdx.x;
  const float4 v = ((const float4*)(x + (size_t)row*1024))[t];
  float ss = v.x*v.x + v.y*v.y + v.z*v.z + v.w*v.w;
#pragma unroll
  for (int m = 32; m; m >>= 1) ss += __shfl_xor(ss, m);
  __shared__ float red[4];
  if ((t & 63) == 0) red[t >> 6] = ss;
  __syncthreads();
  const float tot = red[0] + red[1] + red[2] + red[3];
  const float rs = rsqrtf(tot * (1.0f/1024.0f) + 1.1920929e-07f);
  const float4 wv = ((const float4*)w)[t];
  uint2 o;
  o.x = pk2(f2bf(v.x*rs*wv.x), f2bf(v.y*rs*wv.y));
  o.y = pk2(f2bf(v.z*rs*wv.z), f2bf(v.w*rs*wv.w));
  *(uint2*)&out[(size_t)row*1024 + t*4] = o;
}

// ---------------------------------------------------------------------------
// GEMM: C[M][N] (+)= A[M][K](bf16) * BT[N][K](bf16)^T. m97 structure + XOR
// chunk swizzle (conflict-free ds_read): LDS stays linear (gld16 constraint),
// global source chunk is pre-swizzled ch^=(row&7); frag reads undo it.
// EPI 0: bf16 store (SPLITK must be 1). EPI 2: fp32 atomicAdd.
// ---------------------------------------------------------------------------
template<int BM, int BN, int EPI, int SPLITK>
__global__ __launch_bounds__(256, 2) void gemm_bt(
    const ushort_t* __restrict__ A, const ushort_t* __restrict__ BT,
    void* __restrict__ Cout, int M, int N, int K) {
  constexpr int BK = 64;
  __shared__ ushort_t Al[BM*BK];
  __shared__ ushort_t Bl[BN*BK];
  const int t = threadIdx.x, lane = t & 63;
  const int l15 = lane & 15, l4 = lane >> 4;
  int bid = blockIdx.y * gridDim.x + blockIdx.x;
  const int nwg = gridDim.x * gridDim.y;
  if ((nwg & 7) == 0) bid = (bid & 7) * (nwg >> 3) + (bid >> 3);
  const int n0 = (bid % gridDim.x) * BN;
  const int m0 = (bid / gridDim.x) * BM;
  constexpr int WM = BM/2, WN = BN/2, FM = WM/16, FN = WN/16;
  const int wm = ((t >> 6) >> 1) * WM;
  const int wn = ((t >> 6) & 1) * WN;
  const f32x4 zf = {0.f, 0.f, 0.f, 0.f};
  f32x4 acc[FM][FN];
#pragma unroll
  for (int m = 0; m < FM; m++)
#pragma unroll
    for (int n = 0; n < FN; n++) acc[m][n] = zf;
  constexpr int CA = (BM*BK)/(256*8), CB = (BN*BK)/(256*8);
  const int kz = blockIdx.z * (K / SPLITK);
  const int sw = l15 & 7;   // read-side XOR key (row&7 == l15&7 since wm,16*m are mult of 8)
  for (int k0 = kz; k0 < kz + K / SPLITK; k0 += BK) {
#pragma unroll
    for (int i = 0; i < CA; i++) {
      const int c = i*256 + t, row = c >> 3, ch = (c & 7) ^ (row & 7);
      gld16(&A[(size_t)(m0 + row)*K + k0 + ch*8], &Al[c*8]);
    }
#pragma unroll
    for (int i = 0; i < CB; i++) {
      const int c = i*256 + t, row = c >> 3, ch = (c & 7) ^ (row & 7);
      gld16(&BT[(size_t)(n0 + row)*K + k0 + ch*8], &Bl[c*8]);
    }
    __syncthreads();
#pragma unroll
    for (int kc = 0; kc < BK; kc += 32) {
      bf16x8 af[FM], bfr[FN];
#pragma unroll
      for (int m = 0; m < FM; m++)
        af[m] = *(const bf16x8*)&Al[(wm + m*16 + l15)*BK + (((kc >> 3) + l4) ^ sw)*8];
#pragma unroll
      for (int n = 0; n < FN; n++)
        bfr[n] = *(const bf16x8*)&Bl[(wn + n*16 + l15)*BK + (((kc >> 3) + l4) ^ sw)*8];
#pragma unroll
      for (int m = 0; m < FM; m++)
#pragma unroll
        for (int n = 0; n < FN; n++)
          acc[m][n] = __builtin_amdgcn_mfma_f32_16x16x32_bf16(af[m], bfr[n], acc[m][n], 0, 0, 0);
    }
    __syncthreads();
  }
#pragma unroll
  for (int m = 0; m < FM; m++)
#pragma unroll
    for (int n = 0; n < FN; n++)
#pragma unroll
      for (int r = 0; r < 4; r++) {
        const int row = m0 + wm + m*16 + l4*4 + r;
        const int col = n0 + wn + n*16 + l15;
        const size_t idx = (size_t)row*N + col;
        const float v = acc[m][n][r];
        if (EPI == 0) ((ushort_t*)Cout)[idx] = f2bf(v);
        else          atomicAdd(&((float*)Cout)[idx], v);
      }
}

// ---------------------------------------------------------------------------
// col attention: block = (c,h,b); 32 strided queries x 32 strided keys, fp32 vector
// ---------------------------------------------------------------------------
__global__ __launch_bounds__(256) void attn_col_k(const ushort_t* __restrict__ qkv,
                                                  ushort_t* __restrict__ O) {
  __shared__ float Qs[32][65], Ks[32][65], Vs[32][65], P[32][33];
  const int c = blockIdx.x, h = blockIdx.y, b = blockIdx.z, t = threadIdx.x;
  const size_t base = (size_t)b*1024*3072 + h*64;
  for (int e = t; e < 2048; e += 256) {
    const int u = e >> 6, d = e & 63;
    const size_t rb = base + (size_t)(c + 32*u)*3072 + d;
    Qs[u][d] = bf2f(qkv[rb]);
    Ks[u][d] = bf2f(qkv[rb + 1024]);
    Vs[u][d] = bf2f(qkv[rb + 2048]);
  }
  __syncthreads();
  const int u = t >> 3, kq = (t & 7)*4;
  float sc[4] = {0.f, 0.f, 0.f, 0.f};
  for (int d = 0; d < 64; d++) {
    const float q = Qs[u][d];
#pragma unroll
    for (int j = 0; j < 4; j++) sc[j] += q * Ks[kq + j][d];
  }
#pragma unroll
  for (int j = 0; j < 4; j++) P[u][kq + j] = sc[j] * 0.125f;
  __syncthreads();
  if (t < 32) {
    float mx = P[t][0];
    for (int j = 1; j < 32; j++) mx = fmaxf(mx, P[t][j]);
    float sum = 0.f;
    for (int j = 0; j < 32; j++) { const float p = __expf(P[t][j] - mx); P[t][j] = p; sum += p; }
    const float inv = 1.0f / sum;
    for (int j = 0; j < 32; j++) P[t][j] *= inv;
  }
  __syncthreads();
  const int dg = (t & 7)*8;
  float o[8] = {0.f,0.f,0.f,0.f,0.f,0.f,0.f,0.f};
  for (int k = 0; k < 32; k++) {
    const float p = P[u][k];
#pragma unroll
    for (int j = 0; j < 8; j++) o[j] += p * Vs[k][dg + j];
  }
  uint4 w4;
  w4.x = pk2(f2bf(o[0]), f2bf(o[1])); w4.y = pk2(f2bf(o[2]), f2bf(o[3]));
  w4.z = pk2(f2bf(o[4]), f2bf(o[5])); w4.w = pk2(f2bf(o[6]), f2bf(o[7]));
  *(uint4*)&O[(size_t)(b*1024 + c + 32*u)*1024 + h*64 + dg] = w4;
}

// ---------------------------------------------------------------------------
// MFMA flash attention, 64-key tiles, stride-66 LDS (<=2-way banks), register
// prefetch. MASK: 0=feat(128 block), 1=nbr(band 64), 2=full (NSPLIT k-split).
// ---------------------------------------------------------------------------
template<int MASK, int NSPLIT>
__global__ __launch_bounds__(256) void attn_flash_k(const ushort_t* __restrict__ qkv,
    ushort_t* __restrict__ O, float* __restrict__ Opart, float* __restrict__ MLpart) {
  constexpr int LP = 66;   // row stride: LP/2==33 ==1 mod 32 -> <=2-way banks
  __shared__ ushort_t Kl[64*LP];
  __shared__ ushort_t Vt[64*LP];
  __shared__ ushort_t Pl[4][16*LP];
  const int t = threadIdx.x, lane = t & 63, wave = t >> 6;
  const int l15 = lane & 15, l4 = lane >> 4;
  const int qt = blockIdx.x, h = blockIdx.y;
  const int b = blockIdx.z / NSPLIT, sp = blockIdx.z % NSPLIT;
  const int q0 = qt*64;
  const size_t base = (size_t)b*1024*3072 + h*64;
  const int qrow = q0 + wave*16 + l15;
  const bf16x8 qf0 = *(const bf16x8*)&qkv[base + (size_t)qrow*3072 + l4*8];
  const bf16x8 qf1 = *(const bf16x8*)&qkv[base + (size_t)qrow*3072 + 32 + l4*8];
  int klo, khi;
  if (MASK == 0)      { klo = q0 & ~127; khi = klo + 128; }
  else if (MASK == 1) { klo = (q0 >= 64) ? q0 - 64 : 0; khi = (q0 + 128 < 1024) ? q0 + 128 : 1024; }
  else                { klo = sp * (1024/NSPLIT); khi = klo + 1024/NSPLIT; }
  const int kr = t >> 2, kd = (t & 3)*16;
  const int vk = lane,  vd = wave*16;
  const ushort_t* kptr = qkv + base + 1024 + (size_t)kr*3072 + kd;
  const ushort_t* vptr = qkv + base + 2048 + (size_t)vk*3072 + vd;
  bf16x8 kg0 = *(const bf16x8*)&kptr[(size_t)klo*3072];
  bf16x8 kg1 = *(const bf16x8*)&kptr[(size_t)klo*3072 + 8];
  bf16x8 vg0 = *(const bf16x8*)&vptr[(size_t)klo*3072];
  bf16x8 vg1 = *(const bf16x8*)&vptr[(size_t)klo*3072 + 8];
  const f32x4 zf = {0.f, 0.f, 0.f, 0.f};
  f32x4 of[4];
#pragma unroll
  for (int n = 0; n < 4; n++) of[n] = zf;
  float mrow[4], lrow[4];
#pragma unroll
  for (int r = 0; r < 4; r++) { mrow[r] = -INFINITY; lrow[r] = 0.f; }

  for (int kb = klo; kb < khi; kb += 64) {
    *(bf16x8*)&Kl[kr*LP + kd] = kg0;
    *(bf16x8*)&Kl[kr*LP + kd + 8] = kg1;
#pragma unroll
    for (int j = 0; j < 8; j++) Vt[(vd + j)*LP + vk] = (ushort_t)vg0[j];
#pragma unroll
    for (int j = 0; j < 8; j++) Vt[(vd + 8 + j)*LP + vk] = (ushort_t)vg1[j];
    __syncthreads();
    if (kb + 64 < khi) {   // T14: prefetch next tile into regs
      kg0 = *(const bf16x8*)&kptr[(size_t)(kb+64)*3072];
      kg1 = *(const bf16x8*)&kptr[(size_t)(kb+64)*3072 + 8];
      vg0 = *(const bf16x8*)&vptr[(size_t)(kb+64)*3072];
      vg1 = *(const bf16x8*)&vptr[(size_t)(kb+64)*3072 + 8];
    }
    f32x4 sf[4];
    __builtin_amdgcn_s_setprio(1);
#pragma unroll
    for (int s = 0; s < 4; s++) {
      const bf16x8 k0 = *(const bf16x8*)&Kl[(s*16 + l15)*LP + l4*8];
      const bf16x8 k1 = *(const bf16x8*)&Kl[(s*16 + l15)*LP + 32 + l4*8];
      sf[s] = __builtin_amdgcn_mfma_f32_16x16x32_bf16(qf0, k0, zf, 0, 0, 0);
      sf[s] = __builtin_amdgcn_mfma_f32_16x16x32_bf16(qf1, k1, sf[s], 0, 0, 0);
    }
    __builtin_amdgcn_s_setprio(0);
    float sv[4][4], tmax[4];
#pragma unroll
    for (int r = 0; r < 4; r++) tmax[r] = -INFINITY;
#pragma unroll
    for (int s = 0; s < 4; s++)
#pragma unroll
      for (int r = 0; r < 4; r++) {
        float a = sf[s][r]*0.125f;
        if (MASK == 1) {
          const int d = (q0 + wave*16 + l4*4 + r) - (kb + s*16 + l15);
          if (d > 64 || d < -64) a = -INFINITY;
        }
        sv[s][r] = a;
        tmax[r] = fmaxf(tmax[r], a);
      }
#pragma unroll
    for (int mk = 1; mk < 16; mk <<= 1)
#pragma unroll
      for (int r = 0; r < 4; r++) tmax[r] = fmaxf(tmax[r], __shfl_xor(tmax[r], mk));
    float fac[4], psum[4];
#pragma unroll
    for (int r = 0; r < 4; r++) {
      const float mn = fmaxf(mrow[r], tmax[r]);
      psum[r] = 0.f;
      if (mn == -INFINITY) {
        fac[r] = 1.0f;
#pragma unroll
        for (int s = 0; s < 4; s++) Pl[wave][(l4*4 + r)*LP + s*16 + l15] = 0;
      } else {
        fac[r] = __expf(mrow[r] - mn);
        mrow[r] = mn;
#pragma unroll
        for (int s = 0; s < 4; s++) {
          const float p = __expf(sv[s][r] - mn);
          psum[r] += p;
          Pl[wave][(l4*4 + r)*LP + s*16 + l15] = f2bf(p);
        }
      }
    }
#pragma unroll
    for (int mk = 1; mk < 16; mk <<= 1)
#pragma unroll
      for (int r = 0; r < 4; r++) psum[r] += __shfl_xor(psum[r], mk);
#pragma unroll
    for (int r = 0; r < 4; r++) lrow[r] = lrow[r]*fac[r] + psum[r];
#pragma unroll
    for (int n = 0; n < 4; n++)
#pragma unroll
      for (int r = 0; r < 4; r++) of[n][r] *= fac[r];
    const bf16x8 pa0 = *(const bf16x8*)&Pl[wave][l15*LP + l4*8];
    const bf16x8 pa1 = *(const bf16x8*)&Pl[wave][l15*LP + 32 + l4*8];
    __builtin_amdgcn_s_setprio(1);
#pragma unroll
    for (int n = 0; n < 4; n++) {
      const bf16x8 v0 = *(const bf16x8*)&Vt[(n*16 + l15)*LP + l4*8];
      const bf16x8 v1 = *(const bf16x8*)&Vt[(n*16 + l15)*LP + 32 + l4*8];
      of[n] = __builtin_amdgcn_mfma_f32_16x16x32_bf16(pa0, v0, of[n], 0, 0, 0);
      of[n] = __builtin_amdgcn_mfma_f32_16x16x32_bf16(pa1, v1, of[n], 0, 0, 0);
    }
    __builtin_amdgcn_s_setprio(0);
    __syncthreads();
  }
  if (NSPLIT == 1) {
#pragma unroll
    for (int n = 0; n < 4; n++)
#pragma unroll
      for (int r = 0; r < 4; r++) {
        const int qg = q0 + wave*16 + l4*4 + r;
        O[(size_t)(b*1024 + qg)*1024 + h*64 + n*16 + l15] = f2bf(of[n][r] / lrow[r]);
      }
  } else {
#pragma unroll
    for (int r = 0; r < 4; r++) {
      const int qg = q0 + wave*16 + l4*4 + r;
      const size_t row = ((size_t)(sp*2 + b)*1024 + qg)*16 + h;
#pragma unroll
      for (int n = 0; n < 4; n++) Opart[row*64 + n*16 + l15] = of[n][r];
      if (l15 == 0) *(float2*)&MLpart[row*2] = make_float2(mrow[r], lrow[r]);
    }
  }
}

// merge 2 k-splits
__global__ __launch_bounds__(256) void attn_merge_k(const float* __restrict__ Opart,
    const float* __restrict__ ML, ushort_t* __restrict__ O) {
  const int idx = blockIdx.x*256 + threadIdx.x;
  const int d8 = (idx & 7)*8;
  const int h  = (idx >> 3) & 15;
  const int q  = (idx >> 7) & 1023;
  const int b  = idx >> 17;
  const size_t r0 = ((size_t)b*1024 + q)*16 + h;
  const size_t r1 = ((size_t)(2 + b)*1024 + q)*16 + h;
  const float2 ml0 = *(const float2*)&ML[r0*2];
  const float2 ml1 = *(const float2*)&ML[r1*2];
  const float m = fmaxf(ml0.x, ml1.x);
  const float w0 = __expf(ml0.x - m), w1 = __expf(ml1.x - m);
  const float inv = 1.0f / (ml0.y*w0 + ml1.y*w1);
  const float4* o0 = (const float4*)&Opart[r0*64 + d8];
  const float4* o1 = (const float4*)&Opart[r1*64 + d8];
  ushort_t ob[8];
#pragma unroll
  for (int i = 0; i < 2; i++) {
    const float4 a = o0[i], c = o1[i];
    ob[i*4+0] = f2bf((a.x*w0 + c.x*w1)*inv);
    ob[i*4+1] = f2bf((a.y*w0 + c.y*w1)*inv);
    ob[i*4+2] = f2bf((a.z*w0 + c.z*w1)*inv);
    ob[i*4+3] = f2bf((a.w*w0 + c.w*w1)*inv);
  }
  uint4 w4;
  w4.x = pk2(ob[0], ob[1]); w4.y = pk2(ob[2], ob[3]);
  w4.z = pk2(ob[4], ob[5]); w4.w = pk2(ob[6], ob[7]);
  *(uint4*)&O[((size_t)b*1024 + q)*1024 + h*64 + d8] = w4;
}

// ---------------------------------------------------------------------------
// SwiGLU
// ---------------------------------------------------------------------------
__global__ __launch_bounds__(256) void swiglu_k(const ushort_t* __restrict__ gu,
                                                ushort_t* __restrict__ out) {
  const size_t idx = (size_t)blockIdx.x*256 + threadIdx.x;
  const size_t m = idx >> 9, j8 = (idx & 511) << 3;
  const bf16x8 g8 = *(const bf16x8*)&gu[m*8192 + j8];
  const bf16x8 u8 = *(const bf16x8*)&gu[m*8192 + 4096 + j8];
  ushort_t o[8];
#pragma unroll
  for (int i = 0; i < 8; i++) {
    const float g = bf2f((ushort_t)g8[i]);
    const float u = bf2f((ushort_t)u8[i]);
    o[i] = f2bf(u * g / (1.0f + __expf(-g)));
  }
  uint4 w4;
  w4.x = pk2(o[0], o[1]); w4.y = pk2(o[2], o[3]); w4.z = pk2(o[4], o[5]); w4.w = pk2(o[6], o[7]);
  *(uint4*)&out[m*4096 + j8] = w4;
}

// ---------------------------------------------------------------------------
extern "C" void kernel_launch(void* const* d_in, const int* in_sizes, int n_in,
                              void* d_out, int out_size, void* d_ws, size_t ws_size,
                              hipStream_t stream) {
  (void)in_sizes; (void)n_in; (void)out_size; (void)ws_size;
  const float* x_in = (const float*)d_in[0];
  const float* norm[5] = { (const float*)d_in[5], (const float*)d_in[10], (const float*)d_in[15],
                           (const float*)d_in[20], (const float*)d_in[25] };
  char* w = (char*)d_ws;
  auto alloc = [&](size_t bytes) { char* p = w; w += (bytes + 255) & ~(size_t)255; return p; };
  ushort_t* qkvT = (ushort_t*)alloc(4ull*3072*1024*2);
  ushort_t* woT  = (ushort_t*)alloc(4ull*1024*1024*2);
  ushort_t* guT  = (ushort_t*)alloc(8192ull*1024*2);
  ushort_t* dnT  = (ushort_t*)alloc(4096ull*1024*2);
  float*    xbuf = (float*)  alloc(2048ull*1024*4);
  ushort_t* xn   = (ushort_t*)alloc(2048ull*1024*2);
  ushort_t* qkv  = (ushort_t*)alloc(2048ull*3072*2);
  ushort_t* attO = (ushort_t*)alloc(2048ull*1024*2);
  ushort_t* gu   = (ushort_t*)alloc(2048ull*8192*2);
  ushort_t* hmid = (ushort_t*)alloc(2048ull*4096*2);
  float* Opart  = (float*)gu;      // aliased, disjoint lifetime
  float* MLpart = (float*)hmid;

  Src16 s;
  for (int l = 0; l < 4; l++) {
    s.p[l*4 + 0] = (const float*)d_in[6 + l*5];
    s.p[l*4 + 1] = (const float*)d_in[7 + l*5];
    s.p[l*4 + 2] = (const float*)d_in[8 + l*5];
    s.p[l*4 + 3] = (const float*)d_in[9 + l*5];
  }
  transpose16<<<dim3(32, 32, 16), 256, 0, stream>>>(s, qkvT, woT);
  transpose_cvt<<<dim3(128, 32), 256, 0, stream>>>((const float*)d_in[27], guT, 1024, 4096, 0);    // w_gate
  transpose_cvt<<<dim3(128, 32), 256, 0, stream>>>((const float*)d_in[26], guT, 1024, 4096, 4096); // w_up
  transpose_cvt<<<dim3(32, 128), 256, 0, stream>>>((const float*)d_in[28], dnT, 4096, 1024, 0);    // w_down

  copy_f32<<<2048, 256, 0, stream>>>(x_in, xbuf);

  for (int l = 0; l < 4; l++) {
    rmsnorm_k<<<2048, 256, 0, stream>>>(xbuf, norm[l], xn);
    gemm_bt<128,128,0,1><<<dim3(3072/128, 2048/128), 256, 0, stream>>>(
        xn, qkvT + (size_t)l*3072*1024, qkv, 2048, 3072, 1024);
    if (l == 0)      attn_col_k         <<<dim3(32, 16, 2), 256, 0, stream>>>(qkv, attO);
    else if (l == 1) attn_flash_k<0,1>  <<<dim3(16, 16, 2), 256, 0, stream>>>(qkv, attO, nullptr, nullptr);
    else if (l == 2) attn_flash_k<1,1>  <<<dim3(16, 16, 2), 256, 0, stream>>>(qkv, attO, nullptr, nullptr);
    else {
      attn_flash_k<2,2><<<dim3(16, 16, 4), 256, 0, stream>>>(qkv, nullptr, Opart, MLpart);
      attn_merge_k<<<1024, 256, 0, stream>>>(Opart, MLpart, attO);
    }
    gemm_bt<128,64,2,2><<<dim3(1024/64, 2048/128, 2), 256, 0, stream>>>(
        attO, woT + (size_t)l*1024*1024, xbuf, 2048, 1024, 1024);
  }
  rmsnorm_k<<<2048, 256, 0, stream>>>(xbuf, norm[4], xn);
  gemm_bt<128,128,0,1><<<dim3(8192/128, 2048/128), 256, 0, stream>>>(xn, guT, gu, 2048, 8192, 1024);
  swiglu_k<<<4096, 256, 0, stream>>>(gu, hmid);
  copy_f32<<<2048, 256, 0, stream>>>(xbuf, (float*)d_out);
  gemm_bt<128,128,2,4><<<dim3(1024/128, 2048/128, 4), 256, 0, stream>>>(
      hmid, dnT, d_out, 2048, 1024, 4096);
}